// Round 7
// baseline (1629.462 us; speedup 1.0000x reference)
//
#include <hip/hip_runtime.h>

// Bidirectional GRU (Keras reset_after) B=32,T=128,E=512,U=1024.
// embed-cast -> weight transposes -> x_proj GEMM -> persistent recurrent kernel
// organized as 8 clusters (2 dirs x 4 batch-quarters), cluster = blockIdx&7
// (= XCD under round-robin). Startup verifies sc0 (XCD-L2) coherence with a
// bounded ping-pong; on success h exchange runs through the local L2 (sc0),
// else device-scope (sc0 sc1). Exchange = fragment-ordered epoch-tagged units
// + compact per-wave tag line (coalesced 128B probe). All spins bounded.

using u16 = unsigned short;
using u32 = unsigned int;
typedef __attribute__((ext_vector_type(8))) short bfx8;
typedef __attribute__((ext_vector_type(4))) float f32x4;
typedef __attribute__((ext_vector_type(4))) u32 u32x4;
typedef __attribute__((ext_vector_type(3))) u32 u32x3;

#define B_ 32
#define T_ 128
#define E_ 512
#define U_ 1024
#define NG 3072
#define M_ 4096
#define YN 4194304
// Per-cluster rotation: 32KB fragment-ordered data + tag page.
// data unit (16B slot, 12B used) = {4x bf16 h, u32 epoch tag, pad}
// addr(col c, row r) = (c>>8)*8192 + ((c>>5)&7)*1024 + r*128 + ((c>>3)&3)*32 + ((c>>2)&1)*16
// tags32[s*4+wv] (4B) at rotation offset 32768 (128B line)
#define ROTB 36864
#define CLB  110592          // 3 rotations

__device__ __forceinline__ float bf2f(u16 u) {
  union { u32 i; float f; } v; v.i = (u32)u << 16; return v.f;
}
__device__ __forceinline__ u16 f2bf(float f) {
  union { float f; u32 i; } v; v.f = f;
  u32 r = v.i + 0x7FFFu + ((v.i >> 16) & 1u);
  return (u16)(r >> 16);
}
__device__ __forceinline__ float sigm(float x) { return 1.0f / (1.0f + __expf(-x)); }

__device__ __forceinline__ void load_lds16(const void* g, void* l) {
  __builtin_amdgcn_global_load_lds(
      (const __attribute__((address_space(1))) u32*)g,
      (__attribute__((address_space(3))) u32*)l, 16, 0, 0);
}

// ---------------- P1: embedding gather + cast ----------------
__global__ __launch_bounds__(256) void k_embed(const int* __restrict__ tok,
                                               const float* __restrict__ emb,
                                               u16* __restrict__ X) {
  int idx = blockIdx.x * 256 + threadIdx.x;
  int m = idx >> 6, k8 = (idx & 63) << 3;
  int b = m & 31, t = m >> 5;
  int tk = tok[b * T_ + t];
  const float* s = emb + (size_t)tk * E_ + k8;
  float4 v0 = *(const float4*)s, v1 = *(const float4*)(s + 4);
  bfx8 r;
  r[0]=(short)f2bf(v0.x); r[1]=(short)f2bf(v0.y); r[2]=(short)f2bf(v0.z); r[3]=(short)f2bf(v0.w);
  r[4]=(short)f2bf(v1.x); r[5]=(short)f2bf(v1.y); r[6]=(short)f2bf(v1.z); r[7]=(short)f2bf(v1.w);
  *(bfx8*)(X + (size_t)m * E_ + k8) = r;
}

// ---------------- P2: transpose/cast weights ----------------
__global__ void k_transpose(const float* __restrict__ in, u16* __restrict__ out,
                            int K, int N, int remap) {
  __shared__ float tile[32][33];
  int k0 = blockIdx.x * 32, n0 = blockIdx.y * 32;
  int tx = threadIdx.x, ty = threadIdx.y;
  for (int j = ty; j < 32; j += 8) tile[j][tx] = in[(size_t)(k0 + j) * N + n0 + tx];
  __syncthreads();
  for (int j = ty; j < 32; j += 8) {
    int n = n0 + j;
    int row = remap ? ((((n & 1023) >> 5) * 96) + ((n >> 10) << 5) + (n & 31)) : n;
    out[(size_t)row * K + k0 + tx] = f2bf(tile[tx][j]);
  }
}

// ---------------- G: x_proj GEMM ----------------
__global__ __launch_bounds__(256) void k_xproj(const u16* __restrict__ X,
                                               const u16* __restrict__ WT,
                                               const float* __restrict__ biasF,
                                               const float* __restrict__ biasB,
                                               u16* __restrict__ XP) {
  const int n0 = blockIdx.x * 128, m0 = blockIdx.y * 128, dir = blockIdx.z;
  const float* bias = dir ? biasB : biasF;
  const u16* Wd = WT + (size_t)dir * NG * E_;
  __shared__ __align__(16) u16 As[128 * 64];
  __shared__ __align__(16) u16 Bs[128 * 64];
  const int tid = threadIdx.x;
  const int wave = tid >> 6, lane = tid & 63;
  const int moff = (wave >> 1) * 64, noff = (wave & 1) * 64;
  const int l15 = lane & 15, l4 = lane >> 4;
  f32x4 acc[4][4] = {};
  for (int kt = 0; kt < 8; ++kt) {
    int k0 = kt * 64;
#pragma unroll
    for (int j = 0; j < 4; ++j) {
      int o = j * 4096 + tid * 16;
      int row = o >> 7;
      int kk = (((o & 127) ^ ((row & 7) << 4)) >> 1);
      load_lds16(X  + (size_t)(m0 + row) * E_ + k0 + kk, (char*)As + o);
      load_lds16(Wd + (size_t)(n0 + row) * E_ + k0 + kk, (char*)Bs + o);
    }
    __syncthreads();
#pragma unroll
    for (int Ks = 0; Ks < 2; ++Ks) {
      bfx8 a[4], b[4];
#pragma unroll
      for (int Mt = 0; Mt < 4; ++Mt) {
        int ra = moff + Mt * 16 + l15;
        int ba = (ra << 7) + ((Ks * 32 + l4 * 8) << 1);
        ba ^= (ra & 7) << 4;
        a[Mt] = *(const bfx8*)((const char*)As + ba);
      }
#pragma unroll
      for (int Nt = 0; Nt < 4; ++Nt) {
        int rb = noff + Nt * 16 + l15;
        int bb2 = (rb << 7) + ((Ks * 32 + l4 * 8) << 1);
        bb2 ^= (rb & 7) << 4;
        b[Nt] = *(const bfx8*)((const char*)Bs + bb2);
      }
#pragma unroll
      for (int Mt = 0; Mt < 4; ++Mt)
#pragma unroll
        for (int Nt = 0; Nt < 4; ++Nt)
          acc[Mt][Nt] = __builtin_amdgcn_mfma_f32_16x16x32_bf16(a[Mt], b[Nt], acc[Mt][Nt], 0, 0, 0);
    }
    __syncthreads();
  }
  float bv[4];
#pragma unroll
  for (int Nt = 0; Nt < 4; ++Nt) bv[Nt] = bias[n0 + noff + Nt * 16 + l15];
#pragma unroll
  for (int Mt = 0; Mt < 4; ++Mt)
#pragma unroll
    for (int Nt = 0; Nt < 4; ++Nt)
#pragma unroll
      for (int r = 0; r < 4; ++r) {
        int m = m0 + moff + Mt * 16 + l4 * 4 + r;
        int n = n0 + noff + Nt * 16 + l15;
        XP[((size_t)dir * M_ + m) * NG + n] = f2bf(acc[Mt][Nt][r] + bv[Nt]);
      }
}

// ---------------- R: persistent recurrent kernel ----------------
#define BLD(OFF, DST, PTR, SC) asm volatile("global_load_dwordx3 %0, %1, off offset:" #OFF " " SC : "=v"(DST) : "v"(PTR));
#define BLD16(SC) \
  BLD(0,L[0][0],a0,SC)    BLD(16,L[0][1],a0,SC)   BLD(1024,L[1][0],a0,SC) BLD(1040,L[1][1],a0,SC) \
  BLD(2048,L[2][0],a0,SC) BLD(2064,L[2][1],a0,SC) BLD(3072,L[3][0],a0,SC) BLD(3088,L[3][1],a0,SC) \
  BLD(0,L[4][0],a1,SC)    BLD(16,L[4][1],a1,SC)   BLD(1024,L[5][0],a1,SC) BLD(1040,L[5][1],a1,SC) \
  BLD(2048,L[6][0],a1,SC) BLD(2064,L[6][1],a1,SC) BLD(3072,L[7][0],a1,SC) BLD(3088,L[7][1],a1,SC)
#define LD_SYS(dst, ad) asm volatile("global_load_dword %0, %1, off sc0 sc1\n\ts_waitcnt vmcnt(0)" : "=v"(dst) : "v"(ad) : "memory");
#define LD_L2(dst, ad)  asm volatile("global_load_dword %0, %1, off sc0\n\ts_waitcnt vmcnt(0)" : "=v"(dst) : "v"(ad) : "memory");
#define ST_SYS(ad, vl)  asm volatile("global_store_dword %0, %1, off sc0 sc1" :: "v"(ad), "v"(vl) : "memory");
#define ST_L2(ad, vl)   asm volatile("global_store_dword %0, %1, off sc0" :: "v"(ad), "v"(vl) : "memory");

__global__ __launch_bounds__(256, 1) void k_gru(
    const u16* __restrict__ RW,
    u16* __restrict__ XP,
    const float* __restrict__ bf_, const float* __restrict__ bb_,
    char* __restrict__ comm,
    float* __restrict__ out) {
  const int tid = threadIdx.x;
  const int wave = tid >> 6, lane = tid & 63;
  const int l15 = lane & 15, l4 = lane >> 4;
  const int wg = blockIdx.x;
  const int cl = wg & 7, role = wg >> 3;         // cluster = XCD under round-robin
  const int dir = cl & 1, bq = cl >> 1;
  const int u0 = role * 32;
  __shared__ float pl[4][8][96];
  __shared__ int sh_mode;

  u32* xslot = (u32*)comm;                        // [256] @ 0
  u32* pingp = (u32*)(comm + 1024) + cl * 16;
  u32* ackp  = (u32*)(comm + 1536) + cl * 16;
  u32* modep = (u32*)(comm + 2048) + cl * 16;
  char* Hc   = comm + 4096 + cl * CLB;

  // ---- long-latency preloads first (overlap with startup spins) ----
  const u16* wbase = RW + (size_t)dir * NG * U_ + (size_t)role * 96 * U_;
  bfx8 wf[6][8];
#pragma unroll
  for (int nt = 0; nt < 6; ++nt)
#pragma unroll
    for (int ks = 0; ks < 8; ++ks)
      wf[nt][ks] = *(const bfx8*)(wbase + (size_t)(nt * 16 + l15) * U_ + wave * 256 + ks * 32 + l4 * 8);

  const int row = tid >> 5, cli = tid & 31;       // thread owns (row, col u0+cli)
  const int brow = bq * 8 + row;
  const float* b1p = (dir ? bb_ : bf_) + NG;
  float b10 = b1p[u0 + cli], b11 = b1p[U_ + u0 + cli], b12 = b1p[2 * U_ + u0 + cli];
  u16* xpd = XP + (size_t)dir * M_ * NG;
  u16 xc0, xc1, xc2;
  {
    int t0 = dir ? 127 : 0;
    const u16* xr = xpd + (size_t)(t0 * 32 + brow) * NG + u0 + cli;
    xc0 = xr[0]; xc1 = xr[U_]; xc2 = xr[2 * U_];
  }

  // ---- startup: post XCC, verify sc0 (XCD-L2) coherence, pick mode ----
  if (tid == 0) {
    u32 xcc = ((u32)__builtin_amdgcn_s_getreg(6164)) & 15u;  // HW_REG_XCC_ID
    u32 pv = xcc + 1u;
    ST_SYS(&xslot[wg], pv);
    if (role == 1) {
      u32 c1 = 0xC0FFEEu;
      ST_L2(pingp, c1);
      int g = 0;
      while (1) {
        u32 av; LD_SYS(av, ackp);
        if (av || ++g > (1 << 22)) break;
        __builtin_amdgcn_s_sleep(2);
      }
      u32 c2 = 0xFEED00u;
      ST_L2(pingp, c2);
    }
    u32 m = 0;
    if (role == 0) {
      bool uni = true; u32 x0 = 0;
      int g = 0;
      for (int r = 0; r < 32; ++r) {
        u32 v = 0;
        while (1) {
          LD_SYS(v, &xslot[r * 8 + cl]);
          if (v || ++g > (1 << 22)) break;
          __builtin_amdgcn_s_sleep(2);
        }
        if (!v) uni = false;
        else if (r == 0) x0 = v;
        else uni &= (v == x0);
      }
      m = 2;
      if (uni) {
        bool s1 = false, s2 = false;
        for (int i = 0; i < 8000 && !s1; ++i) {
          u32 v; LD_L2(v, pingp);
          s1 = (v == 0xC0FFEEu);
          if (!s1) __builtin_amdgcn_s_sleep(2);
        }
        u32 one = 1u;
        ST_SYS(ackp, one);
        if (s1) {
          for (int i = 0; i < 8000 && !s2; ++i) {
            u32 v; LD_L2(v, pingp);
            s2 = (v == 0xFEED00u);
            if (!s2) __builtin_amdgcn_s_sleep(2);
          }
        }
        if (s1 && s2) m = 1;
      }
      ST_SYS(modep, m);
    }
    {
      int g = 0;
      while (1) {
        LD_SYS(m, modep);
        if (m || ++g > (1 << 22)) break;
        __builtin_amdgcn_s_sleep(2);
      }
      if (!m) m = 2;
    }
    if (role == 1) { u32 dd = 0xDEAD01u; ST_L2(pingp, dd); }
    sh_mode = (int)m;
  }
  __syncthreads();
  const int l2m = (sh_mode == 1);

  float hl = 0.f;
  // consumer: wave-region fragment base (l15<8 lanes only)
  const int coff = wave * 8192 + l15 * 128 + l4 * 32;
  // producer: unit byte offset + per-wave tag offset (slice = role)
  const int soff = (role >> 3) * 8192 + (role & 7) * 1024 + row * 128 +
                   ((cli >> 3)) * 32 + (((cli >> 2) & 1)) * 16;
  const int tgoff = 32768 + (role * 4 + wave) * 4;
  // probe: 32 tags for this wave's 8 producer slices (contiguous 128B)
  const int poff = 32768 + (wave * 32 + lane) * 4;

  int rl = 0, rs = 1;
  for (int e = 0; e < 128; ++e) {
    f32x4 acc[6] = {};
    if (e > 0) {
      const u32 etag = (u32)e;
      char* rbase = Hc + rl * ROTB;
      {  // coalesced probe: one 128B line, all 32 producer-wave tags
        const char* pa = rbase + poff;
        u32 tv = etag;
        int g = 0;
        while (1) {
          if (lane < 32) {
            if (l2m) { LD_L2(tv, pa) } else { LD_SYS(tv, pa) }
          }
          if (__all((int)(tv == etag))) break;
          if (++g > (1 << 20)) break;
          __builtin_amdgcn_s_sleep(1);
        }
      }
      // bulk fragment load, once (per-unit tags backstop store reorder)
      u32x3 L[8][2];
      int guard = 0;
      while (1) {
        u32 bad = 0;
        if (l15 < 8) {
          const char* a0 = rbase + coff;
          const char* a1 = a0 + 4096;
          if (l2m) { BLD16("sc0") } else { BLD16("sc0 sc1") }
          asm volatile("s_waitcnt vmcnt(0)");
#pragma unroll
          for (int ks = 0; ks < 8; ++ks)
            asm volatile("" : "+v"(L[ks][0]), "+v"(L[ks][1]));
#pragma unroll
          for (int ks = 0; ks < 8; ++ks)
            bad |= (L[ks][0].z ^ etag) | (L[ks][1].z ^ etag);
        }
        if (__all((int)(bad == 0))) break;
        if (++guard > (1 << 18)) break;            // fail visibly, never hang
        __builtin_amdgcn_s_sleep(1);
      }
      bfx8 af[8] = {};
      if (l15 < 8) {
#pragma unroll
        for (int ks = 0; ks < 8; ++ks) {
          u32x4 fv = {L[ks][0].x, L[ks][0].y, L[ks][1].x, L[ks][1].y};
          af[ks] = __builtin_bit_cast(bfx8, fv);
        }
      }
      __builtin_amdgcn_sched_barrier(0);
#pragma unroll
      for (int ks = 0; ks < 8; ++ks)
#pragma unroll
        for (int nt = 0; nt < 6; ++nt)
          acc[nt] = __builtin_amdgcn_mfma_f32_16x16x32_bf16(af[ks], wf[nt][ks], acc[nt], 0, 0, 0);
    }
    // prefetch next step's x AFTER the gate (HBM latency never inside a spin)
    u16 xn0 = xc0, xn1 = xc1, xn2 = xc2;
    if (e < 127) {
      int tn = dir ? (126 - e) : (e + 1);
      const u16* xr = xpd + (size_t)(tn * 32 + brow) * NG + u0 + cli;
      xn0 = xr[0]; xn1 = xr[U_]; xn2 = xr[2 * U_];
    }
    // dump partials (C rows 0..7): col=lane&15, row=(lane>>4)*4+r
    if (l4 < 2) {
#pragma unroll
      for (int nt = 0; nt < 6; ++nt)
#pragma unroll
        for (int r = 0; r < 4; ++r)
          pl[wave][l4 * 4 + r][nt * 16 + l15] = acc[nt][r];
    }
    __syncthreads();
    // deferred y for epoch e-1 (hl pre-update). Safe: the 4 waves' gates union
    // over all 32 cluster slices => everyone consumed XP row t(e-1) already.
    if (e > 0) {
      int tp = dir ? (128 - e) : (e - 1);
      ((float*)(xpd + (size_t)(tp * 32 + brow) * NG))[u0 + cli] = hl;
    }
    // reduce K-quarters + gates (1 h per thread)
    float red0 = pl[0][row][cli]      + pl[1][row][cli]      + pl[2][row][cli]      + pl[3][row][cli];
    float red1 = pl[0][row][32 + cli] + pl[1][row][32 + cli] + pl[2][row][32 + cli] + pl[3][row][32 + cli];
    float red2 = pl[0][row][64 + cli] + pl[1][row][64 + cli] + pl[2][row][64 + cli] + pl[3][row][64 + cli];
    float z  = sigm(bf2f(xc0) + red0 + b10);
    float r  = sigm(bf2f(xc1) + red1 + b11);
    float hh = tanhf(bf2f(xc2) + r * (red2 + b12));
    hl = z * hl + (1.f - z) * hh;
    // publish: fragment-ordered 12B units, then this wave's tag (program order;
    // per-unit tags catch any store reorder at the consumer)
    if (e < 127) {
      u32 hb = f2bf(hl);
      u32 o1 = __shfl_xor(hb, 1);
      u32 p = (lane & 1) ? (o1 | (hb << 16)) : (hb | (o1 << 16));
      u32 q = __shfl_xor(p, 2);
      char* rw = Hc + rs * ROTB;
      if ((lane & 3) == 0) {
        u32x3 sv; sv.x = p; sv.y = q; sv.z = (u32)(e + 1);
        char* sa = rw + soff;
        if (l2m) asm volatile("global_store_dwordx3 %0, %1, off sc0" :: "v"(sa), "v"(sv) : "memory");
        else     asm volatile("global_store_dwordx3 %0, %1, off sc0 sc1" :: "v"(sa), "v"(sv) : "memory");
      }
      if (lane == 0) {
        u32 tv = (u32)(e + 1);
        char* ta = rw + tgoff;
        if (l2m) { ST_L2(ta, tv) } else { ST_SYS(ta, tv) }
      }
    }
    rl = rs; rs = (rs == 2) ? 0 : rs + 1;
    xc0 = xn0; xc1 = xn1; xc2 = xn2;
    __syncthreads();
  }
  // final y row + states. No wait needed: passing gate 127 proved every peer
  // finished epoch 126 (their t=127 x-prefetch already retired).
  {
    int tl = dir ? 0 : 127;
    ((float*)(xpd + (size_t)(tl * 32 + brow) * NG))[u0 + cli] = hl;
    out[YN + (size_t)dir * (B_ * U_) + (size_t)brow * U_ + u0 + cli] = hl;
  }
}

// ---------------- M: y merge  out = yf + yb ----------------
__global__ __launch_bounds__(256) void k_merge(const u16* __restrict__ XP,
                                               float* __restrict__ out) {
  int idx = blockIdx.x * 256 + threadIdx.x;
  int u4 = (idx & 255) * 4;
  int m = idx >> 8;                            // t*32+b
  int t = m >> 5, b = m & 31;
  const float* yf = (const float*)(XP + (size_t)m * NG);
  const float* yb = (const float*)(XP + (size_t)(M_ + m) * NG);
  float4 a = *(const float4*)(yf + u4);
  float4 c = *(const float4*)(yb + u4);
  float4 o; o.x = a.x + c.x; o.y = a.y + c.y; o.z = a.z + c.z; o.w = a.w + c.w;
  *(float4*)(out + ((size_t)b * T_ + t) * U_ + u4) = o;
}

extern "C" void kernel_launch(void* const* d_in, const int* in_sizes, int n_in,
                              void* d_out, int out_size, void* d_ws, size_t ws_size,
                              hipStream_t stream) {
  const int*   tokens = (const int*)d_in[0];
  const float* emb    = (const float*)d_in[1];
  const float* kf     = (const float*)d_in[2];
  const float* rkf    = (const float*)d_in[3];
  const float* bf_    = (const float*)d_in[4];
  const float* kb     = (const float*)d_in[5];
  const float* rkb    = (const float*)d_in[6];
  const float* bb_    = (const float*)d_in[7];
  float* out = (float*)d_out;
  char* ws = (char*)d_ws;

  // workspace layout. comm ALIASES WT (WT dead after k_xproj; memset is
  // stream-ordered after k_xproj, before k_gru). Full comm cleared each call
  // to remove ALL cross-replay tag staleness.
  u16*  X    = (u16*)ws;                      // 4 MB
  u16*  WT   = (u16*)(ws + 0x400000);         // 6 MB
  char* comm = ws + 0x400000;                 // 4KB hdr + 8*108KB Hx (aliases WT)
  u16*  RW   = (u16*)(ws + 0xA00000);         // 12 MB
  u16*  XP   = (u16*)(ws + 0x1600000);        // 48 MB (y stashed in row heads)

  k_embed<<<1024, 256, 0, stream>>>(tokens, emb, X);
  k_transpose<<<dim3(16, 96), dim3(32, 8), 0, stream>>>(kf,  WT,               512,  NG, 0);
  k_transpose<<<dim3(16, 96), dim3(32, 8), 0, stream>>>(kb,  WT + 3072 * 512,  512,  NG, 0);
  k_transpose<<<dim3(32, 96), dim3(32, 8), 0, stream>>>(rkf, RW,               1024, NG, 1);
  k_transpose<<<dim3(32, 96), dim3(32, 8), 0, stream>>>(rkb, RW + 3072 * 1024, 1024, NG, 1);
  k_xproj<<<dim3(24, 32, 2), 256, 0, stream>>>(X, WT, bf_, bb_, XP);
  hipMemsetAsync(comm, 0, 4096 + 8 * CLB, stream);
  k_gru<<<256, 256, 0, stream>>>(RW, XP, bf_, bb_, comm, out);
  k_merge<<<4096, 256, 0, stream>>>(XP, out);
}

// Round 8
// 644.478 us; speedup vs baseline: 2.5283x; 2.5283x over previous
//
#include <hip/hip_runtime.h>

// Bidirectional GRU (Keras reset_after) B=32,T=128,E=512,U=1024.
// embed-cast -> weight transposes -> x_proj GEMM -> persistent recurrent kernel
// (R4-proven 64-WG structure: epoch-tagged self-validating h exchange, sc0sc1)
// + x-prefetch one epoch ahead (keeps HBM latency out of the gate's vmcnt(0))
// + publish-before-y-write + bounded spins -> y merge.

using u16 = unsigned short;
using u32 = unsigned int;
typedef __attribute__((ext_vector_type(8))) short bfx8;
typedef __attribute__((ext_vector_type(4))) float f32x4;
typedef __attribute__((ext_vector_type(4))) u32 u32x4;
typedef __attribute__((ext_vector_type(3))) u32 u32x3;
typedef __attribute__((ext_vector_type(4))) u16 u16x4;

#define B_ 32
#define T_ 128
#define E_ 512
#define U_ 1024
#define NG 3072
#define M_ 4096
#define YN 4194304
// Hx geometry: per dir, 3 rotating buffers; each [256 grp][32 b][16B]
// unit = {bf16 h[4g..4g+3] for row b (8B), u32 epoch tag, 4B pad}
#define ROTB 131072
#define HXD  393216

__device__ __forceinline__ float bf2f(u16 u) {
  union { u32 i; float f; } v; v.i = (u32)u << 16; return v.f;
}
__device__ __forceinline__ u16 f2bf(float f) {
  union { float f; u32 i; } v; v.f = f;
  u32 r = v.i + 0x7FFFu + ((v.i >> 16) & 1u);
  return (u16)(r >> 16);
}
__device__ __forceinline__ float sigm(float x) { return 1.0f / (1.0f + __expf(-x)); }

__device__ __forceinline__ void load_lds16(const void* g, void* l) {
  __builtin_amdgcn_global_load_lds(
      (const __attribute__((address_space(1))) u32*)g,
      (__attribute__((address_space(3))) u32*)l, 16, 0, 0);
}

// ---------------- P1: embedding gather + cast ----------------
__global__ __launch_bounds__(256) void k_embed(const int* __restrict__ tok,
                                               const float* __restrict__ emb,
                                               u16* __restrict__ X) {
  int idx = blockIdx.x * 256 + threadIdx.x;
  int m = idx >> 6, k8 = (idx & 63) << 3;
  int b = m & 31, t = m >> 5;
  int tk = tok[b * T_ + t];
  const float* s = emb + (size_t)tk * E_ + k8;
  float4 v0 = *(const float4*)s, v1 = *(const float4*)(s + 4);
  bfx8 r;
  r[0]=(short)f2bf(v0.x); r[1]=(short)f2bf(v0.y); r[2]=(short)f2bf(v0.z); r[3]=(short)f2bf(v0.w);
  r[4]=(short)f2bf(v1.x); r[5]=(short)f2bf(v1.y); r[6]=(short)f2bf(v1.z); r[7]=(short)f2bf(v1.w);
  *(bfx8*)(X + (size_t)m * E_ + k8) = r;
}

// ---------------- P2: transpose/cast weights ----------------
__global__ void k_transpose(const float* __restrict__ in, u16* __restrict__ out,
                            int K, int N, int remap) {
  __shared__ float tile[32][33];
  int k0 = blockIdx.x * 32, n0 = blockIdx.y * 32;
  int tx = threadIdx.x, ty = threadIdx.y;
  for (int j = ty; j < 32; j += 8) tile[j][tx] = in[(size_t)(k0 + j) * N + n0 + tx];
  __syncthreads();
  for (int j = ty; j < 32; j += 8) {
    int n = n0 + j;
    int row = remap ? ((((n & 1023) >> 5) * 96) + ((n >> 10) << 5) + (n & 31)) : n;
    out[(size_t)row * K + k0 + tx] = f2bf(tile[tx][j]);
  }
}

// ---------------- G: x_proj GEMM ----------------
__global__ __launch_bounds__(256) void k_xproj(const u16* __restrict__ X,
                                               const u16* __restrict__ WT,
                                               const float* __restrict__ biasF,
                                               const float* __restrict__ biasB,
                                               u16* __restrict__ XP) {
  const int n0 = blockIdx.x * 128, m0 = blockIdx.y * 128, dir = blockIdx.z;
  const float* bias = dir ? biasB : biasF;
  const u16* Wd = WT + (size_t)dir * NG * E_;
  __shared__ __align__(16) u16 As[128 * 64];
  __shared__ __align__(16) u16 Bs[128 * 64];
  const int tid = threadIdx.x;
  const int wave = tid >> 6, lane = tid & 63;
  const int moff = (wave >> 1) * 64, noff = (wave & 1) * 64;
  const int l15 = lane & 15, l4 = lane >> 4;
  f32x4 acc[4][4] = {};
  for (int kt = 0; kt < 8; ++kt) {
    int k0 = kt * 64;
#pragma unroll
    for (int j = 0; j < 4; ++j) {
      int o = j * 4096 + tid * 16;
      int row = o >> 7;
      int kk = (((o & 127) ^ ((row & 7) << 4)) >> 1);
      load_lds16(X  + (size_t)(m0 + row) * E_ + k0 + kk, (char*)As + o);
      load_lds16(Wd + (size_t)(n0 + row) * E_ + k0 + kk, (char*)Bs + o);
    }
    __syncthreads();
#pragma unroll
    for (int Ks = 0; Ks < 2; ++Ks) {
      bfx8 a[4], b[4];
#pragma unroll
      for (int Mt = 0; Mt < 4; ++Mt) {
        int ra = moff + Mt * 16 + l15;
        int ba = (ra << 7) + ((Ks * 32 + l4 * 8) << 1);
        ba ^= (ra & 7) << 4;
        a[Mt] = *(const bfx8*)((const char*)As + ba);
      }
#pragma unroll
      for (int Nt = 0; Nt < 4; ++Nt) {
        int rb = noff + Nt * 16 + l15;
        int bb2 = (rb << 7) + ((Ks * 32 + l4 * 8) << 1);
        bb2 ^= (rb & 7) << 4;
        b[Nt] = *(const bfx8*)((const char*)Bs + bb2);
      }
#pragma unroll
      for (int Mt = 0; Mt < 4; ++Mt)
#pragma unroll
        for (int Nt = 0; Nt < 4; ++Nt)
          acc[Mt][Nt] = __builtin_amdgcn_mfma_f32_16x16x32_bf16(a[Mt], b[Nt], acc[Mt][Nt], 0, 0, 0);
    }
    __syncthreads();
  }
  float bv[4];
#pragma unroll
  for (int Nt = 0; Nt < 4; ++Nt) bv[Nt] = bias[n0 + noff + Nt * 16 + l15];
#pragma unroll
  for (int Mt = 0; Mt < 4; ++Mt)
#pragma unroll
    for (int Nt = 0; Nt < 4; ++Nt)
#pragma unroll
      for (int r = 0; r < 4; ++r) {
        int m = m0 + moff + Mt * 16 + l4 * 4 + r;
        int n = n0 + noff + Nt * 16 + l15;
        XP[((size_t)dir * M_ + m) * NG + n] = f2bf(acc[Mt][Nt][r] + bv[Nt]);
      }
}

// ---------------- R: persistent recurrent kernel (R4 structure) ----------------
// 64 WGs = 2 dirs x 32 slices. h exchange via epoch-tagged 12B-in-16B units:
// a load returning tag==e atomically carries step-e data. 3-buffer rotation.
// Deltas vs R4: x prefetched one epoch ahead (gate's vmcnt(0) never waits on
// HBM), publish before deferred-y, bounded spins.
__global__ __launch_bounds__(256, 1) void k_gru(
    const u16* __restrict__ RW,
    u16* __restrict__ XP,
    const float* __restrict__ bf_, const float* __restrict__ bb_,
    char* __restrict__ Hx,
    float* __restrict__ out) {
  const int tid = threadIdx.x;
  const int wave = tid >> 6, lane = tid & 63;
  const int wg = blockIdx.x;
  const int dir = wg & 1, slice = wg >> 1;
  const int u0 = slice * 32;
  const float* b1p = (dir ? bb_ : bf_) + NG;
  const u16* wbase = RW + (size_t)dir * NG * U_ + (size_t)slice * 96 * U_;
  u16* xpd = XP + (size_t)dir * M_ * NG;
  char* hxd = Hx + (size_t)dir * HXD;
  __shared__ float pl[4][32][97];

  const int l15 = lane & 15, l4 = lane >> 4;

  // preload this wave's 48 weight frags — resident all 128 steps
  bfx8 wf[6][8];
#pragma unroll
  for (int Nt = 0; Nt < 6; ++Nt)
#pragma unroll
    for (int Ks = 0; Ks < 8; ++Ks) {
      int c = Nt * 16 + l15;
      int k = wave * 256 + Ks * 32 + l4 * 8;
      wf[Nt][Ks] = *(const bfx8*)(wbase + (size_t)c * U_ + k);
    }

  // epilogue mapping: thread owns (b=eb, cols u0+uu..u0+uu+3)
  const int eb = tid & 31;
  const int ug = tid >> 5;
  const int uu = ug * 4;
  float b1[3][4];
#pragma unroll
  for (int g = 0; g < 3; ++g)
#pragma unroll
    for (int j = 0; j < 4; ++j) b1[g][j] = b1p[g * U_ + u0 + uu + j];
  float hreg[4] = {0.f, 0.f, 0.f, 0.f};

  const int offb = wave * 32768 + l4 * 1024 + l15 * 16;          // consumer bulk base
  const int sp = wave * 8 + (lane & 7);
  const int poff = (8 * sp + 7) * 512 + 31 * 16 + 8;             // probe tag addr
  const int soff = (slice * 8 + ug) * 512 + eb * 16;             // producer unit

  // x for step 0, loaded up-front (prefetched one epoch ahead thereafter)
  u16x4 xc[3];
  {
    int t0 = dir ? 127 : 0;
    const u16* xr = xpd + (size_t)(t0 * 32 + eb) * NG + u0 + uu;
#pragma unroll
    for (int g = 0; g < 3; ++g) xc[g] = *(const u16x4*)(xr + g * U_);
  }

  int rl = 0, rs = 1;                              // rl = e%3, rs = (e+1)%3
  for (int e = 0; e < 128; ++e) {
    f32x4 acc[2][6] = {};
    if (e > 0) {
      const u32 etag = (u32)e;
      char* rbase = hxd + rl * ROTB;
      // -- probe poll (cheap): one tag per producer slice in this wave's K-range
      {
        const char* pa = rbase + poff;
        u32 tv = etag;
        int g = 0;
        while (1) {
          if (lane < 8) {
            asm volatile("global_load_dword %0, %1, off sc0 sc1\n\ts_waitcnt vmcnt(0)"
                         : "=v"(tv) : "v"(pa));
          }
          if (__all((int)(tv == etag))) break;
          if (++g > (1 << 20)) break;              // fail visibly, never hang
          __builtin_amdgcn_s_sleep(1);
        }
      }
      // -- bulk self-validating load of all 16 h fragments
      u32x3 L[2][8][2];
      int guard = 0;
      while (1) {
#pragma unroll
        for (int Ks = 0; Ks < 8; ++Ks) {
          const char* a = rbase + offb + Ks * 4096;
          asm volatile("global_load_dwordx3 %0, %1, off sc0 sc1"             : "=v"(L[0][Ks][0]) : "v"(a));
          asm volatile("global_load_dwordx3 %0, %1, off offset:512 sc0 sc1" : "=v"(L[0][Ks][1]) : "v"(a));
          asm volatile("global_load_dwordx3 %0, %1, off offset:256 sc0 sc1" : "=v"(L[1][Ks][0]) : "v"(a));
          asm volatile("global_load_dwordx3 %0, %1, off offset:768 sc0 sc1" : "=v"(L[1][Ks][1]) : "v"(a));
        }
        asm volatile("s_waitcnt vmcnt(0)");
#pragma unroll
        for (int Mt = 0; Mt < 2; ++Mt)
#pragma unroll
          for (int Ks = 0; Ks < 8; ++Ks)
            asm volatile("" : "+v"(L[Mt][Ks][0]), "+v"(L[Mt][Ks][1]));
        u32 bad = 0;
#pragma unroll
        for (int Mt = 0; Mt < 2; ++Mt)
#pragma unroll
          for (int Ks = 0; Ks < 8; ++Ks)
            bad |= (L[Mt][Ks][0].z ^ etag) | (L[Mt][Ks][1].z ^ etag);
        if (__all((int)(bad == 0))) break;
        if (++guard > (1 << 18)) break;            // fail visibly, never hang
        __builtin_amdgcn_s_sleep(1);
      }
      // -- extract fragments and run MFMA
      bfx8 af[2][8];
#pragma unroll
      for (int Mt = 0; Mt < 2; ++Mt)
#pragma unroll
        for (int Ks = 0; Ks < 8; ++Ks) {
          u32x4 fv = {L[Mt][Ks][0].x, L[Mt][Ks][0].y, L[Mt][Ks][1].x, L[Mt][Ks][1].y};
          af[Mt][Ks] = __builtin_bit_cast(bfx8, fv);
        }
      // prefetch x for step e+1 NOW (consumed next epoch; retired long before
      // the next gate's vmcnt(0) — the whole compute phase covers its latency)
      u16x4 xn[3];
      bool pf = (e < 127);
      if (pf) {
        int tn = dir ? (126 - e) : (e + 1);
        const u16* xr = xpd + (size_t)(tn * 32 + eb) * NG + u0 + uu;
#pragma unroll
        for (int g = 0; g < 3; ++g) xn[g] = *(const u16x4*)(xr + g * U_);
      }
      __builtin_amdgcn_sched_barrier(0);
#pragma unroll
      for (int Ks = 0; Ks < 8; ++Ks)
#pragma unroll
        for (int Mt = 0; Mt < 2; ++Mt)
#pragma unroll
          for (int Nt = 0; Nt < 6; ++Nt)
            acc[Mt][Nt] = __builtin_amdgcn_mfma_f32_16x16x32_bf16(af[Mt][Ks], wf[Nt][Ks],
                                                                  acc[Mt][Nt], 0, 0, 0);
      // stash prefetch for the epilogue (after dump/reduce)
      if (pf) {
        // fallthrough below via xn copy at end of loop body — keep in regs
      }
      // dump partials: C/D layout col=lane&15, row=(lane>>4)*4+r
#pragma unroll
      for (int Mt = 0; Mt < 2; ++Mt)
#pragma unroll
        for (int Nt = 0; Nt < 6; ++Nt)
#pragma unroll
          for (int r = 0; r < 4; ++r)
            pl[wave][Mt * 16 + l4 * 4 + r][Nt * 16 + l15] = acc[Mt][Nt][r];
      __syncthreads();
      // reduce K-quarters + gates; publish FIRST, then deferred y (pre-update h)
      float hold[4];
#pragma unroll
      for (int j = 0; j < 4; ++j) hold[j] = hreg[j];
#pragma unroll
      for (int j = 0; j < 4; ++j) {
        int c = uu + j;
        float rz = pl[0][eb][c]      + pl[1][eb][c]      + pl[2][eb][c]      + pl[3][eb][c];
        float rr = pl[0][eb][32 + c] + pl[1][eb][32 + c] + pl[2][eb][32 + c] + pl[3][eb][32 + c];
        float rh = pl[0][eb][64 + c] + pl[1][eb][64 + c] + pl[2][eb][64 + c] + pl[3][eb][64 + c];
        float z  = sigm(bf2f(xc[0][j]) + rz + b1[0][j]);
        float r  = sigm(bf2f(xc[1][j]) + rr + b1[1][j]);
        float hh = tanhf(bf2f(xc[2][j]) + r * (rh + b1[2][j]));
        hreg[j] = z * hreg[j] + (1.f - z) * hh;
      }
      {
        u32 p01 = (u32)f2bf(hreg[0]) | ((u32)f2bf(hreg[1]) << 16);
        u32 p23 = (u32)f2bf(hreg[2]) | ((u32)f2bf(hreg[3]) << 16);
        u32x3 sv; sv.x = p01; sv.y = p23; sv.z = (u32)(e + 1);
        char* sa = hxd + rs * ROTB + soff;
        asm volatile("global_store_dwordx3 %0, %1, off sc0 sc1" :: "v"(sa), "v"(sv));
      }
      // deferred y for epoch e-1. Safe: the 4 waves' gates union over all 32
      // slices => every WG consumed XP row t(e-1) (x consumed before publish).
      {
        const int tp = dir ? (128 - e) : (e - 1);
        float* yrow = (float*)(xpd + (size_t)(tp * 32 + eb) * NG);
        *(float4*)(yrow + u0 + uu) = make_float4(hold[0], hold[1], hold[2], hold[3]);
      }
      if (pf) { xc[0] = xn[0]; xc[1] = xn[1]; xc[2] = xn[2]; }
    } else {
      // e == 0: h=0 -> rec contribution is zero; prefetch x(t=1)
      u16x4 xn[3];
      {
        int tn = dir ? 126 : 1;
        const u16* xr = xpd + (size_t)(tn * 32 + eb) * NG + u0 + uu;
#pragma unroll
        for (int g = 0; g < 3; ++g) xn[g] = *(const u16x4*)(xr + g * U_);
      }
#pragma unroll
      for (int j = 0; j < 4; ++j) {
        float z  = sigm(bf2f(xc[0][j]) + b1[0][j]);
        float r  = sigm(bf2f(xc[1][j]) + b1[1][j]);
        float hh = tanhf(bf2f(xc[2][j]) + r * b1[2][j]);
        hreg[j] = (1.f - z) * hh;
      }
      {
        u32 p01 = (u32)f2bf(hreg[0]) | ((u32)f2bf(hreg[1]) << 16);
        u32 p23 = (u32)f2bf(hreg[2]) | ((u32)f2bf(hreg[3]) << 16);
        u32x3 sv; sv.x = p01; sv.y = p23; sv.z = 1u;
        char* sa = hxd + rs * ROTB + soff;
        asm volatile("global_store_dwordx3 %0, %1, off sc0 sc1" :: "v"(sa), "v"(sv));
      }
      xc[0] = xn[0]; xc[1] = xn[1]; xc[2] = xn[2];
    }
    rl = rs; rs = (rs == 2) ? 0 : rs + 1;
    __syncthreads();          // protect pl against next epoch's dump
  }
  // final: wait for all 32 slices' tag-128 (rot 2) — proves every peer
  // consumed row t=127's x — then write last y row + final states.
  {
    const char* pa = hxd + 2 * ROTB + (8 * (lane & 31) + 7) * 512 + 31 * 16 + 8;
    u32 tv = 128u;
    int g = 0;
    while (1) {
      if (lane < 32) {
        asm volatile("global_load_dword %0, %1, off sc0 sc1\n\ts_waitcnt vmcnt(0)"
                     : "=v"(tv) : "v"(pa));
      }
      if (__all((int)(tv == 128u))) break;
      if (++g > (1 << 22)) break;
      __builtin_amdgcn_s_sleep(1);
    }
    const int tl = dir ? 0 : 127;
    float* yrow = (float*)(xpd + (size_t)(tl * 32 + eb) * NG);
    *(float4*)(yrow + u0 + uu) = make_float4(hreg[0], hreg[1], hreg[2], hreg[3]);
    float* os = out + YN + (size_t)dir * (B_ * U_) + (size_t)eb * U_ + u0 + uu;
    *(float4*)os = make_float4(hreg[0], hreg[1], hreg[2], hreg[3]);
  }
}

// ---------------- M: y merge  out = yf + yb ----------------
__global__ __launch_bounds__(256) void k_merge(const u16* __restrict__ XP,
                                               float* __restrict__ out) {
  int idx = blockIdx.x * 256 + threadIdx.x;
  int u4 = (idx & 255) * 4;
  int m = idx >> 8;                            // t*32+b
  int t = m >> 5, b = m & 31;
  const float* yf = (const float*)(XP + (size_t)m * NG);
  const float* yb = (const float*)(XP + (size_t)(M_ + m) * NG);
  float4 a = *(const float4*)(yf + u4);
  float4 c = *(const float4*)(yb + u4);
  float4 o; o.x = a.x + c.x; o.y = a.y + c.y; o.z = a.z + c.z; o.w = a.w + c.w;
  *(float4*)(out + ((size_t)b * T_ + t) * U_ + u4) = o;
}

extern "C" void kernel_launch(void* const* d_in, const int* in_sizes, int n_in,
                              void* d_out, int out_size, void* d_ws, size_t ws_size,
                              hipStream_t stream) {
  const int*   tokens = (const int*)d_in[0];
  const float* emb    = (const float*)d_in[1];
  const float* kf     = (const float*)d_in[2];
  const float* rkf    = (const float*)d_in[3];
  const float* bf_    = (const float*)d_in[4];
  const float* kb     = (const float*)d_in[5];
  const float* rkb    = (const float*)d_in[6];
  const float* bb_    = (const float*)d_in[7];
  float* out = (float*)d_out;
  char* ws = (char*)d_ws;

  // workspace layout. Hx ALIASES WT (WT dead after k_xproj; memset is
  // stream-ordered after k_xproj, before k_gru).
  u16*  X  = (u16*)ws;                        // 4 MB
  u16*  WT = (u16*)(ws + 0x400000);           // 6 MB
  char* Hx = ws + 0x400000;                   // 768 KB (aliases WT)
  u16*  RW = (u16*)(ws + 0xA00000);           // 12 MB
  u16*  XP = (u16*)(ws + 0x1600000);          // 48 MB (y stashed in row heads)

  k_embed<<<1024, 256, 0, stream>>>(tokens, emb, X);
  k_transpose<<<dim3(16, 96), dim3(32, 8), 0, stream>>>(kf,  WT,               512,  NG, 0);
  k_transpose<<<dim3(16, 96), dim3(32, 8), 0, stream>>>(kb,  WT + 3072 * 512,  512,  NG, 0);
  k_transpose<<<dim3(32, 96), dim3(32, 8), 0, stream>>>(rkf, RW,               1024, NG, 1);
  k_transpose<<<dim3(32, 96), dim3(32, 8), 0, stream>>>(rkb, RW + 3072 * 1024, 1024, NG, 1);
  k_xproj<<<dim3(24, 32, 2), 256, 0, stream>>>(X, WT, bf_, bb_, XP);
  hipMemsetAsync(Hx, 0, 2 * HXD, stream);     // clear epoch tags (also per replay)
  k_gru<<<64, 256, 0, stream>>>(RW, XP, bf_, bb_, Hx, out);
  k_merge<<<4096, 256, 0, stream>>>(XP, out);
}

// Round 9
// 627.037 us; speedup vs baseline: 2.5987x; 1.0278x over previous
//
#include <hip/hip_runtime.h>

// Bidirectional GRU (Keras reset_after) B=32,T=128,E=512,U=1024.
// embed-cast -> weight transposes -> x_proj GEMM -> persistent recurrent kernel
// (64-WG structure; epoch-tagged self-validating h exchange over sc0sc1).
// R9 deltas vs R8: probe removed (self-validating bulk IS the gate, saving one
// L3 round trip per step) + 16B dwordx4 units + fast tanh. -> y merge.

using u16 = unsigned short;
using u32 = unsigned int;
typedef __attribute__((ext_vector_type(8))) short bfx8;
typedef __attribute__((ext_vector_type(4))) float f32x4;
typedef __attribute__((ext_vector_type(4))) u32 u32x4;
typedef __attribute__((ext_vector_type(4))) u16 u16x4;

#define B_ 32
#define T_ 128
#define E_ 512
#define U_ 1024
#define NG 3072
#define M_ 4096
#define YN 4194304
// Hx geometry: per dir, 3 rotating buffers; each [256 grp][32 b][16B]
// unit = {bf16 h[4g..4g+3] for row b (8B), u32 epoch tag, u32 tag copy}
#define ROTB 131072
#define HXD  393216

__device__ __forceinline__ float bf2f(u16 u) {
  union { u32 i; float f; } v; v.i = (u32)u << 16; return v.f;
}
__device__ __forceinline__ u16 f2bf(float f) {
  union { float f; u32 i; } v; v.f = f;
  u32 r = v.i + 0x7FFFu + ((v.i >> 16) & 1u);
  return (u16)(r >> 16);
}
__device__ __forceinline__ float sigm(float x) { return 1.0f / (1.0f + __expf(-x)); }
__device__ __forceinline__ float ftanh(float x) {
  float e = __expf(2.f * x);          // saturation-safe: +inf -> 1, 0 -> -1
  return 1.f - 2.f / (e + 1.f);
}

__device__ __forceinline__ void load_lds16(const void* g, void* l) {
  __builtin_amdgcn_global_load_lds(
      (const __attribute__((address_space(1))) u32*)g,
      (__attribute__((address_space(3))) u32*)l, 16, 0, 0);
}

// ---------------- P1: embedding gather + cast ----------------
__global__ __launch_bounds__(256) void k_embed(const int* __restrict__ tok,
                                               const float* __restrict__ emb,
                                               u16* __restrict__ X) {
  int idx = blockIdx.x * 256 + threadIdx.x;
  int m = idx >> 6, k8 = (idx & 63) << 3;
  int b = m & 31, t = m >> 5;
  int tk = tok[b * T_ + t];
  const float* s = emb + (size_t)tk * E_ + k8;
  float4 v0 = *(const float4*)s, v1 = *(const float4*)(s + 4);
  bfx8 r;
  r[0]=(short)f2bf(v0.x); r[1]=(short)f2bf(v0.y); r[2]=(short)f2bf(v0.z); r[3]=(short)f2bf(v0.w);
  r[4]=(short)f2bf(v1.x); r[5]=(short)f2bf(v1.y); r[6]=(short)f2bf(v1.z); r[7]=(short)f2bf(v1.w);
  *(bfx8*)(X + (size_t)m * E_ + k8) = r;
}

// ---------------- P2: transpose/cast weights ----------------
__global__ void k_transpose(const float* __restrict__ in, u16* __restrict__ out,
                            int K, int N, int remap) {
  __shared__ float tile[32][33];
  int k0 = blockIdx.x * 32, n0 = blockIdx.y * 32;
  int tx = threadIdx.x, ty = threadIdx.y;
  for (int j = ty; j < 32; j += 8) tile[j][tx] = in[(size_t)(k0 + j) * N + n0 + tx];
  __syncthreads();
  for (int j = ty; j < 32; j += 8) {
    int n = n0 + j;
    int row = remap ? ((((n & 1023) >> 5) * 96) + ((n >> 10) << 5) + (n & 31)) : n;
    out[(size_t)row * K + k0 + tx] = f2bf(tile[tx][j]);
  }
}

// ---------------- G: x_proj GEMM ----------------
__global__ __launch_bounds__(256) void k_xproj(const u16* __restrict__ X,
                                               const u16* __restrict__ WT,
                                               const float* __restrict__ biasF,
                                               const float* __restrict__ biasB,
                                               u16* __restrict__ XP) {
  const int n0 = blockIdx.x * 128, m0 = blockIdx.y * 128, dir = blockIdx.z;
  const float* bias = dir ? biasB : biasF;
  const u16* Wd = WT + (size_t)dir * NG * E_;
  __shared__ __align__(16) u16 As[128 * 64];
  __shared__ __align__(16) u16 Bs[128 * 64];
  const int tid = threadIdx.x;
  const int wave = tid >> 6, lane = tid & 63;
  const int moff = (wave >> 1) * 64, noff = (wave & 1) * 64;
  const int l15 = lane & 15, l4 = lane >> 4;
  f32x4 acc[4][4] = {};
  for (int kt = 0; kt < 8; ++kt) {
    int k0 = kt * 64;
#pragma unroll
    for (int j = 0; j < 4; ++j) {
      int o = j * 4096 + tid * 16;
      int row = o >> 7;
      int kk = (((o & 127) ^ ((row & 7) << 4)) >> 1);
      load_lds16(X  + (size_t)(m0 + row) * E_ + k0 + kk, (char*)As + o);
      load_lds16(Wd + (size_t)(n0 + row) * E_ + k0 + kk, (char*)Bs + o);
    }
    __syncthreads();
#pragma unroll
    for (int Ks = 0; Ks < 2; ++Ks) {
      bfx8 a[4], b[4];
#pragma unroll
      for (int Mt = 0; Mt < 4; ++Mt) {
        int ra = moff + Mt * 16 + l15;
        int ba = (ra << 7) + ((Ks * 32 + l4 * 8) << 1);
        ba ^= (ra & 7) << 4;
        a[Mt] = *(const bfx8*)((const char*)As + ba);
      }
#pragma unroll
      for (int Nt = 0; Nt < 4; ++Nt) {
        int rb = noff + Nt * 16 + l15;
        int bb2 = (rb << 7) + ((Ks * 32 + l4 * 8) << 1);
        bb2 ^= (rb & 7) << 4;
        b[Nt] = *(const bfx8*)((const char*)Bs + bb2);
      }
#pragma unroll
      for (int Mt = 0; Mt < 4; ++Mt)
#pragma unroll
        for (int Nt = 0; Nt < 4; ++Nt)
          acc[Mt][Nt] = __builtin_amdgcn_mfma_f32_16x16x32_bf16(a[Mt], b[Nt], acc[Mt][Nt], 0, 0, 0);
    }
    __syncthreads();
  }
  float bv[4];
#pragma unroll
  for (int Nt = 0; Nt < 4; ++Nt) bv[Nt] = bias[n0 + noff + Nt * 16 + l15];
#pragma unroll
  for (int Mt = 0; Mt < 4; ++Mt)
#pragma unroll
    for (int Nt = 0; Nt < 4; ++Nt)
#pragma unroll
      for (int r = 0; r < 4; ++r) {
        int m = m0 + moff + Mt * 16 + l4 * 4 + r;
        int n = n0 + noff + Nt * 16 + l15;
        XP[((size_t)dir * M_ + m) * NG + n] = f2bf(acc[Mt][Nt][r] + bv[Nt]);
      }
}

// ---------------- R: persistent recurrent kernel ----------------
// 64 WGs = 2 dirs x 32 slices. h exchange via epoch-tagged 16B units:
// a dwordx4 load returning tag==e atomically carries step-e data -> the bulk
// load IS the gate (no probe round trip). 3-buffer rotation (proof as R4).
__global__ __launch_bounds__(256, 1) void k_gru(
    const u16* __restrict__ RW,
    u16* __restrict__ XP,
    const float* __restrict__ bf_, const float* __restrict__ bb_,
    char* __restrict__ Hx,
    float* __restrict__ out) {
  const int tid = threadIdx.x;
  const int wave = tid >> 6, lane = tid & 63;
  const int wg = blockIdx.x;
  const int dir = wg & 1, slice = wg >> 1;
  const int u0 = slice * 32;
  const float* b1p = (dir ? bb_ : bf_) + NG;
  const u16* wbase = RW + (size_t)dir * NG * U_ + (size_t)slice * 96 * U_;
  u16* xpd = XP + (size_t)dir * M_ * NG;
  char* hxd = Hx + (size_t)dir * HXD;
  __shared__ float pl[4][32][97];

  const int l15 = lane & 15, l4 = lane >> 4;

  // preload this wave's 48 weight frags — resident all 128 steps
  bfx8 wf[6][8];
#pragma unroll
  for (int Nt = 0; Nt < 6; ++Nt)
#pragma unroll
    for (int Ks = 0; Ks < 8; ++Ks) {
      int c = Nt * 16 + l15;
      int k = wave * 256 + Ks * 32 + l4 * 8;
      wf[Nt][Ks] = *(const bfx8*)(wbase + (size_t)c * U_ + k);
    }

  // epilogue mapping: thread owns (b=eb, cols u0+uu..u0+uu+3)
  const int eb = tid & 31;
  const int ug = tid >> 5;
  const int uu = ug * 4;
  float b1[3][4];
#pragma unroll
  for (int g = 0; g < 3; ++g)
#pragma unroll
    for (int j = 0; j < 4; ++j) b1[g][j] = b1p[g * U_ + u0 + uu + j];
  float hreg[4] = {0.f, 0.f, 0.f, 0.f};

  const int offb = wave * 32768 + l4 * 1024 + l15 * 16;          // consumer bulk base
  const int soff = (slice * 8 + ug) * 512 + eb * 16;             // producer unit

  // xc holds CURRENT step's x; loaded up-front for step 0
  u16x4 xc[3];
  {
    int t0 = dir ? 127 : 0;
    const u16* xr = xpd + (size_t)(t0 * 32 + eb) * NG + u0 + uu;
#pragma unroll
    for (int g = 0; g < 3; ++g) xc[g] = *(const u16x4*)(xr + g * U_);
  }

  int rl = 0, rs = 1;                              // rl = e%3, rs = (e+1)%3
  for (int e = 0; e < 128; ++e) {
    f32x4 acc[2][6] = {};
    u16x4 xn[3] = {xc[0], xc[1], xc[2]};           // next-step x (default keep)
    if (e > 0) {
      const u32 etag = (u32)e;
      char* rbase = hxd + rl * ROTB;
      // -- self-validating bulk load: the load IS the gate (no probe RT)
      u32x4 L[2][8], L2[2][8];
      int guard = 0;
      while (1) {
#pragma unroll
        for (int Ks = 0; Ks < 8; ++Ks) {
          const char* a = rbase + offb + Ks * 4096;
          asm volatile("global_load_dwordx4 %0, %1, off sc0 sc1"             : "=v"(L[0][Ks])  : "v"(a));
          asm volatile("global_load_dwordx4 %0, %1, off offset:256 sc0 sc1" : "=v"(L2[0][Ks]) : "v"(a));
          asm volatile("global_load_dwordx4 %0, %1, off offset:512 sc0 sc1" : "=v"(L[1][Ks])  : "v"(a));
          asm volatile("global_load_dwordx4 %0, %1, off offset:768 sc0 sc1" : "=v"(L2[1][Ks]) : "v"(a));
        }
        asm volatile("s_waitcnt vmcnt(0)");
#pragma unroll
        for (int h = 0; h < 2; ++h)
#pragma unroll
          for (int Ks = 0; Ks < 8; ++Ks)
            asm volatile("" : "+v"(L[h][Ks]), "+v"(L2[h][Ks]));
        u32 bad = 0;
#pragma unroll
        for (int h = 0; h < 2; ++h)
#pragma unroll
          for (int Ks = 0; Ks < 8; ++Ks)
            bad |= (L[h][Ks].z ^ etag) | (L2[h][Ks].z ^ etag);
        if (__all((int)(bad == 0))) break;
        if (++guard > (1 << 18)) break;            // fail visibly, never hang
        __builtin_amdgcn_s_sleep(1);
      }
      // fragments: af[Mt][Ks]; Mt=0 from (L[0],L[1]) rows 0-15, Mt=1 from L2
      bfx8 af[2][8];
#pragma unroll
      for (int Ks = 0; Ks < 8; ++Ks) {
        u32x4 f0 = {L[0][Ks].x, L[0][Ks].y, L[1][Ks].x, L[1][Ks].y};
        u32x4 f1 = {L2[0][Ks].x, L2[0][Ks].y, L2[1][Ks].x, L2[1][Ks].y};
        af[0][Ks] = __builtin_bit_cast(bfx8, f0);
        af[1][Ks] = __builtin_bit_cast(bfx8, f1);
      }
      // prefetch next step's x (fully shadowed by the MFMA phase)
      if (e < 127) {
        int tn = dir ? (126 - e) : (e + 1);
        const u16* xr = xpd + (size_t)(tn * 32 + eb) * NG + u0 + uu;
#pragma unroll
        for (int g = 0; g < 3; ++g) xn[g] = *(const u16x4*)(xr + g * U_);
      }
      __builtin_amdgcn_sched_barrier(0);
#pragma unroll
      for (int Ks = 0; Ks < 8; ++Ks)
#pragma unroll
        for (int Mt = 0; Mt < 2; ++Mt)
#pragma unroll
          for (int Nt = 0; Nt < 6; ++Nt)
            acc[Mt][Nt] = __builtin_amdgcn_mfma_f32_16x16x32_bf16(af[Mt][Ks], wf[Nt][Ks],
                                                                  acc[Mt][Nt], 0, 0, 0);
    } else {
      // e==0: rec contribution is zero; prefetch x for step 1
      int tn = dir ? 126 : 1;
      const u16* xr = xpd + (size_t)(tn * 32 + eb) * NG + u0 + uu;
#pragma unroll
      for (int g = 0; g < 3; ++g) xn[g] = *(const u16x4*)(xr + g * U_);
    }
    // dump partials: C/D layout col=lane&15, row=(lane>>4)*4+r
#pragma unroll
    for (int Mt = 0; Mt < 2; ++Mt)
#pragma unroll
      for (int Nt = 0; Nt < 6; ++Nt)
#pragma unroll
        for (int r = 0; r < 4; ++r)
          pl[wave][Mt * 16 + l4 * 4 + r][Nt * 16 + l15] = acc[Mt][Nt][r];
    __syncthreads();
    // reduce K-quarters + gates; publish FIRST, then deferred y (pre-update h)
    float hold[4];
#pragma unroll
    for (int j = 0; j < 4; ++j) hold[j] = hreg[j];
#pragma unroll
    for (int j = 0; j < 4; ++j) {
      int c = uu + j;
      float rz = pl[0][eb][c]      + pl[1][eb][c]      + pl[2][eb][c]      + pl[3][eb][c];
      float rr = pl[0][eb][32 + c] + pl[1][eb][32 + c] + pl[2][eb][32 + c] + pl[3][eb][32 + c];
      float rh = pl[0][eb][64 + c] + pl[1][eb][64 + c] + pl[2][eb][64 + c] + pl[3][eb][64 + c];
      float z  = sigm(bf2f(xc[0][j]) + rz + b1[0][j]);
      float r  = sigm(bf2f(xc[1][j]) + rr + b1[1][j]);
      float hh = ftanh(bf2f(xc[2][j]) + r * (rh + b1[2][j]));
      hreg[j] = z * hreg[j] + (1.f - z) * hh;
    }
    {
      u32 p01 = (u32)f2bf(hreg[0]) | ((u32)f2bf(hreg[1]) << 16);
      u32 p23 = (u32)f2bf(hreg[2]) | ((u32)f2bf(hreg[3]) << 16);
      u32x4 sv; sv.x = p01; sv.y = p23; sv.z = (u32)(e + 1); sv.w = (u32)(e + 1);
      char* sa = hxd + rs * ROTB + soff;
      asm volatile("global_store_dwordx4 %0, %1, off sc0 sc1" :: "v"(sa), "v"(sv));
    }
    // deferred y for epoch e-1. Safe: the gates' union over all 32 slices
    // proves every WG consumed XP row t(e-1) before publishing tag e.
    if (e > 0) {
      const int tp = dir ? (128 - e) : (e - 1);
      float* yrow = (float*)(xpd + (size_t)(tp * 32 + eb) * NG);
      *(float4*)(yrow + u0 + uu) = make_float4(hold[0], hold[1], hold[2], hold[3]);
    }
    xc[0] = xn[0]; xc[1] = xn[1]; xc[2] = xn[2];
    rl = rs; rs = (rs == 2) ? 0 : rs + 1;
    __syncthreads();          // protect pl against next epoch's dump
  }
  // final: wait for all 32 slices' tag-128 (rot 2), then last y row + states
  {
    const char* pa = hxd + 2 * ROTB + ((lane & 31) * 8 + 7) * 512 + 31 * 16;
    int g = 0;
    while (1) {
      u32 tv = 128u;
      if (lane < 32) {
        u32x4 tvv;
        asm volatile("global_load_dwordx4 %0, %1, off sc0 sc1\n\ts_waitcnt vmcnt(0)"
                     : "=v"(tvv) : "v"(pa));
        tv = tvv.z;
      }
      if (__all((int)(tv == 128u))) break;
      if (++g > (1 << 22)) break;
      __builtin_amdgcn_s_sleep(1);
    }
    const int tl = dir ? 0 : 127;
    float* yrow = (float*)(xpd + (size_t)(tl * 32 + eb) * NG);
    *(float4*)(yrow + u0 + uu) = make_float4(hreg[0], hreg[1], hreg[2], hreg[3]);
    float* os = out + YN + (size_t)dir * (B_ * U_) + (size_t)eb * U_ + u0 + uu;
    *(float4*)os = make_float4(hreg[0], hreg[1], hreg[2], hreg[3]);
  }
}

// ---------------- M: y merge  out = yf + yb ----------------
__global__ __launch_bounds__(256) void k_merge(const u16* __restrict__ XP,
                                               float* __restrict__ out) {
  int idx = blockIdx.x * 256 + threadIdx.x;
  int u4 = (idx & 255) * 4;
  int m = idx >> 8;                            // t*32+b
  int t = m >> 5, b = m & 31;
  const float* yf = (const float*)(XP + (size_t)m * NG);
  const float* yb = (const float*)(XP + (size_t)(M_ + m) * NG);
  float4 a = *(const float4*)(yf + u4);
  float4 c = *(const float4*)(yb + u4);
  float4 o; o.x = a.x + c.x; o.y = a.y + c.y; o.z = a.z + c.z; o.w = a.w + c.w;
  *(float4*)(out + ((size_t)b * T_ + t) * U_ + u4) = o;
}

extern "C" void kernel_launch(void* const* d_in, const int* in_sizes, int n_in,
                              void* d_out, int out_size, void* d_ws, size_t ws_size,
                              hipStream_t stream) {
  const int*   tokens = (const int*)d_in[0];
  const float* emb    = (const float*)d_in[1];
  const float* kf     = (const float*)d_in[2];
  const float* rkf    = (const float*)d_in[3];
  const float* bf_    = (const float*)d_in[4];
  const float* kb     = (const float*)d_in[5];
  const float* rkb    = (const float*)d_in[6];
  const float* bb_    = (const float*)d_in[7];
  float* out = (float*)d_out;
  char* ws = (char*)d_ws;

  u16*  X  = (u16*)ws;                        // 4 MB
  u16*  WT = (u16*)(ws + 0x400000);           // 6 MB
  char* Hx = ws + 0x400000;                   // 768 KB (aliases WT; WT dead)
  u16*  RW = (u16*)(ws + 0xA00000);           // 12 MB
  u16*  XP = (u16*)(ws + 0x1600000);          // 48 MB (y stashed in row heads)

  k_embed<<<1024, 256, 0, stream>>>(tokens, emb, X);
  k_transpose<<<dim3(16, 96), dim3(32, 8), 0, stream>>>(kf,  WT,               512,  NG, 0);
  k_transpose<<<dim3(16, 96), dim3(32, 8), 0, stream>>>(kb,  WT + 3072 * 512,  512,  NG, 0);
  k_transpose<<<dim3(32, 96), dim3(32, 8), 0, stream>>>(rkf, RW,               1024, NG, 1);
  k_transpose<<<dim3(32, 96), dim3(32, 8), 0, stream>>>(rkb, RW + 3072 * 1024, 1024, NG, 1);
  k_xproj<<<dim3(24, 32, 2), 256, 0, stream>>>(X, WT, bf_, bb_, XP);
  hipMemsetAsync(Hx, 0, 2 * HXD, stream);
  k_gru<<<64, 256, 0, stream>>>(RW, XP, bf_, bb_, Hx, out);
  k_merge<<<4096, 256, 0, stream>>>(XP, out);
}

// Round 11
// 619.883 us; speedup vs baseline: 2.6287x; 1.0115x over previous
//
#include <hip/hip_runtime.h>

// Bidirectional GRU (Keras reset_after) B=32,T=128,E=512,U=1024.
// embed-cast -> fused weight transpose -> x_proj GEMM -> persistent recurrent
// kernel (R9-proven 64-WG structure; epoch-tagged self-validating h exchange
// over sc0sc1) with TWO-PHASE gate: validate+MFMA chunks 0-3 under vmcnt(16)
// while chunks 4-7 are still in flight -> y merge.

using u16 = unsigned short;
using u32 = unsigned int;
typedef __attribute__((ext_vector_type(8))) short bfx8;
typedef __attribute__((ext_vector_type(4))) float f32x4;
typedef __attribute__((ext_vector_type(4))) u32 u32x4;
typedef __attribute__((ext_vector_type(4))) u16 u16x4;

#define B_ 32
#define T_ 128
#define E_ 512
#define U_ 1024
#define NG 3072
#define M_ 4096
#define YN 4194304
// Hx geometry: per dir, 3 rotating buffers; each [256 grp][32 b][16B]
// unit = {bf16 h[4g..4g+3] for row b (8B), u32 epoch tag, u32 tag copy}
#define ROTB 131072
#define HXD  393216

__device__ __forceinline__ float bf2f(u16 u) {
  union { u32 i; float f; } v; v.i = (u32)u << 16; return v.f;
}
__device__ __forceinline__ u16 f2bf(float f) {
  union { float f; u32 i; } v; v.f = f;
  u32 r = v.i + 0x7FFFu + ((v.i >> 16) & 1u);
  return (u16)(r >> 16);
}
__device__ __forceinline__ float sigm(float x) { return 1.0f / (1.0f + __expf(-x)); }
__device__ __forceinline__ float ftanh(float x) {
  float e = __expf(2.f * x);          // saturation-safe: +inf -> 1, 0 -> -1
  return 1.f - 2.f / (e + 1.f);
}

__device__ __forceinline__ void load_lds16(const void* g, void* l) {
  __builtin_amdgcn_global_load_lds(
      (const __attribute__((address_space(1))) u32*)g,
      (__attribute__((address_space(3))) u32*)l, 16, 0, 0);
}

// ---------------- P1: embedding gather + cast ----------------
__global__ __launch_bounds__(256) void k_embed(const int* __restrict__ tok,
                                               const float* __restrict__ emb,
                                               u16* __restrict__ X) {
  int idx = blockIdx.x * 256 + threadIdx.x;
  int m = idx >> 6, k8 = (idx & 63) << 3;
  int b = m & 31, t = m >> 5;
  int tk = tok[b * T_ + t];
  const float* s = emb + (size_t)tk * E_ + k8;
  float4 v0 = *(const float4*)s, v1 = *(const float4*)(s + 4);
  bfx8 r;
  r[0]=(short)f2bf(v0.x); r[1]=(short)f2bf(v0.y); r[2]=(short)f2bf(v0.z); r[3]=(short)f2bf(v0.w);
  r[4]=(short)f2bf(v1.x); r[5]=(short)f2bf(v1.y); r[6]=(short)f2bf(v1.z); r[7]=(short)f2bf(v1.w);
  *(bfx8*)(X + (size_t)m * E_ + k8) = r;
}

// ---------------- P2: fused transpose/cast of all 4 weight matrices ----------------
// grid (48, 96, 2): z = dir; x<16 -> kernel (K=512, no remap), x>=16 -> rec
// kernel (K=1024, remap to GRU-slice packing).
__global__ void k_transpose_all(const float* __restrict__ kf, const float* __restrict__ kb,
                                const float* __restrict__ rkf, const float* __restrict__ rkb,
                                u16* __restrict__ WT, u16* __restrict__ RW) {
  __shared__ float tile[32][33];
  const int z = blockIdx.z;
  const float* in; u16* outp; int K, remap, bx;
  if (blockIdx.x < 16) { in = z ? kb : kf;   outp = WT + (size_t)z * 3072 * 512;  K = 512;  remap = 0; bx = blockIdx.x; }
  else                 { in = z ? rkb : rkf; outp = RW + (size_t)z * 3072 * 1024; K = 1024; remap = 1; bx = blockIdx.x - 16; }
  int k0 = bx * 32, n0 = blockIdx.y * 32;
  int tx = threadIdx.x, ty = threadIdx.y;
  for (int j = ty; j < 32; j += 8) tile[j][tx] = in[(size_t)(k0 + j) * NG + n0 + tx];
  __syncthreads();
  for (int j = ty; j < 32; j += 8) {
    int n = n0 + j;
    int row = remap ? ((((n & 1023) >> 5) * 96) + ((n >> 10) << 5) + (n & 31)) : n;
    outp[(size_t)row * K + k0 + tx] = f2bf(tile[tx][j]);
  }
}

// ---------------- G: x_proj GEMM ----------------
__global__ __launch_bounds__(256) void k_xproj(const u16* __restrict__ X,
                                               const u16* __restrict__ WT,
                                               const float* __restrict__ biasF,
                                               const float* __restrict__ biasB,
                                               u16* __restrict__ XP) {
  const int n0 = blockIdx.x * 128, m0 = blockIdx.y * 128, dir = blockIdx.z;
  const float* bias = dir ? biasB : biasF;
  const u16* Wd = WT + (size_t)dir * NG * E_;
  __shared__ __align__(16) u16 As[128 * 64];
  __shared__ __align__(16) u16 Bs[128 * 64];
  const int tid = threadIdx.x;
  const int wave = tid >> 6, lane = tid & 63;
  const int moff = (wave >> 1) * 64, noff = (wave & 1) * 64;
  const int l15 = lane & 15, l4 = lane >> 4;
  f32x4 acc[4][4] = {};
  for (int kt = 0; kt < 8; ++kt) {
    int k0 = kt * 64;
#pragma unroll
    for (int j = 0; j < 4; ++j) {
      int o = j * 4096 + tid * 16;
      int row = o >> 7;
      int kk = (((o & 127) ^ ((row & 7) << 4)) >> 1);
      load_lds16(X  + (size_t)(m0 + row) * E_ + k0 + kk, (char*)As + o);
      load_lds16(Wd + (size_t)(n0 + row) * E_ + k0 + kk, (char*)Bs + o);
    }
    __syncthreads();
#pragma unroll
    for (int Ks = 0; Ks < 2; ++Ks) {
      bfx8 a[4], b[4];
#pragma unroll
      for (int Mt = 0; Mt < 4; ++Mt) {
        int ra = moff + Mt * 16 + l15;
        int ba = (ra << 7) + ((Ks * 32 + l4 * 8) << 1);
        ba ^= (ra & 7) << 4;
        a[Mt] = *(const bfx8*)((const char*)As + ba);
      }
#pragma unroll
      for (int Nt = 0; Nt < 4; ++Nt) {
        int rb = noff + Nt * 16 + l15;
        int bb2 = (rb << 7) + ((Ks * 32 + l4 * 8) << 1);
        bb2 ^= (rb & 7) << 4;
        b[Nt] = *(const bfx8*)((const char*)Bs + bb2);
      }
#pragma unroll
      for (int Mt = 0; Mt < 4; ++Mt)
#pragma unroll
        for (int Nt = 0; Nt < 4; ++Nt)
          acc[Mt][Nt] = __builtin_amdgcn_mfma_f32_16x16x32_bf16(a[Mt], b[Nt], acc[Mt][Nt], 0, 0, 0);
    }
    __syncthreads();
  }
  float bv[4];
#pragma unroll
  for (int Nt = 0; Nt < 4; ++Nt) bv[Nt] = bias[n0 + noff + Nt * 16 + l15];
#pragma unroll
  for (int Mt = 0; Mt < 4; ++Mt)
#pragma unroll
    for (int Nt = 0; Nt < 4; ++Nt)
#pragma unroll
      for (int r = 0; r < 4; ++r) {
        int m = m0 + moff + Mt * 16 + l4 * 4 + r;
        int n = n0 + noff + Nt * 16 + l15;
        XP[((size_t)dir * M_ + m) * NG + n] = f2bf(acc[Mt][Nt][r] + bv[Nt]);
      }
}

// ---------------- R: persistent recurrent kernel ----------------
// 64 WGs = 2 dirs x 32 slices. Epoch-tagged 16B units; TWO-PHASE gate:
// group A (chunks 0-3) validated at vmcnt(16) and MFMA'd while group B
// (chunks 4-7) is still in flight; then B at vmcnt(0). Retries re-issue only
// the failed group. 3-buffer rotation (proof as R4/R9).
#define GISS(Ks) { \
  const char* a_ = rbase + offb + (Ks) * 4096; \
  asm volatile("global_load_dwordx4 %0, %1, off sc0 sc1"             : "=v"(L[0][Ks])  : "v"(a_)); \
  asm volatile("global_load_dwordx4 %0, %1, off offset:256 sc0 sc1" : "=v"(L2[0][Ks]) : "v"(a_)); \
  asm volatile("global_load_dwordx4 %0, %1, off offset:512 sc0 sc1" : "=v"(L[1][Ks])  : "v"(a_)); \
  asm volatile("global_load_dwordx4 %0, %1, off offset:768 sc0 sc1" : "=v"(L2[1][Ks]) : "v"(a_)); }

__global__ __launch_bounds__(256, 1) void k_gru(
    const u16* __restrict__ RW,
    u16* __restrict__ XP,
    const float* __restrict__ bf_, const float* __restrict__ bb_,
    char* __restrict__ Hx,
    float* __restrict__ out) {
  const int tid = threadIdx.x;
  const int wave = tid >> 6, lane = tid & 63;
  const int wg = blockIdx.x;
  const int dir = wg & 1, slice = wg >> 1;
  const int u0 = slice * 32;
  const float* b1p = (dir ? bb_ : bf_) + NG;
  const u16* wbase = RW + (size_t)dir * NG * U_ + (size_t)slice * 96 * U_;
  u16* xpd = XP + (size_t)dir * M_ * NG;
  char* hxd = Hx + (size_t)dir * HXD;
  __shared__ float pl[4][32][97];

  const int l15 = lane & 15, l4 = lane >> 4;

  // preload this wave's 48 weight frags — resident all 128 steps
  bfx8 wf[6][8];
#pragma unroll
  for (int Nt = 0; Nt < 6; ++Nt)
#pragma unroll
    for (int Ks = 0; Ks < 8; ++Ks) {
      int c = Nt * 16 + l15;
      int k = wave * 256 + Ks * 32 + l4 * 8;
      wf[Nt][Ks] = *(const bfx8*)(wbase + (size_t)c * U_ + k);
    }

  // epilogue mapping: thread owns (b=eb, cols u0+uu..u0+uu+3)
  const int eb = tid & 31;
  const int ug = tid >> 5;
  const int uu = ug * 4;
  float b1[3][4];
#pragma unroll
  for (int g = 0; g < 3; ++g)
#pragma unroll
    for (int j = 0; j < 4; ++j) b1[g][j] = b1p[g * U_ + u0 + uu + j];
  float hreg[4] = {0.f, 0.f, 0.f, 0.f};

  const int offb = wave * 32768 + l4 * 1024 + l15 * 16;          // consumer bulk base
  const int soff = (slice * 8 + ug) * 512 + eb * 16;             // producer unit

  // xc holds CURRENT step's x; loaded up-front for step 0
  u16x4 xc[3];
  {
    int t0 = dir ? 127 : 0;
    const u16* xr = xpd + (size_t)(t0 * 32 + eb) * NG + u0 + uu;
#pragma unroll
    for (int g = 0; g < 3; ++g) xc[g] = *(const u16x4*)(xr + g * U_);
  }

  int rl = 0, rs = 1;                              // rl = e%3, rs = (e+1)%3
  for (int e = 0; e < 128; ++e) {
    f32x4 acc[2][6] = {};
    u16x4 xn[3] = {xc[0], xc[1], xc[2]};           // next-step x (default keep)
    if (e > 0) {
      const u32 etag = (u32)e;
      char* rbase = hxd + rl * ROTB;
      u32x4 L[2][8], L2[2][8];
      // issue ALL 32 unit loads: group A (Ks 0-3) oldest, group B (Ks 4-7)
      GISS(0) GISS(1) GISS(2) GISS(3)
      GISS(4) GISS(5) GISS(6) GISS(7)
      // ---- phase A: vmcnt(16) -> in-order retirement means A retired ----
      {
        asm volatile("s_waitcnt vmcnt(16)");
        int guard = 0;
        while (1) {
          u32 bad = 0;
#pragma unroll
          for (int Ks = 0; Ks < 4; ++Ks) {
            asm volatile("" : "+v"(L[0][Ks]), "+v"(L2[0][Ks]), "+v"(L[1][Ks]), "+v"(L2[1][Ks]));
            bad |= (L[0][Ks].z ^ etag) | (L2[0][Ks].z ^ etag) |
                   (L[1][Ks].z ^ etag) | (L2[1][Ks].z ^ etag);
          }
          if (__all((int)(bad == 0))) break;
          if (++guard > (1 << 18)) break;          // fail visibly, never hang
          __builtin_amdgcn_s_sleep(1);
          GISS(0) GISS(1) GISS(2) GISS(3)
          asm volatile("s_waitcnt vmcnt(0)");
        }
      }
      bfx8 afA[2][4];
#pragma unroll
      for (int Ks = 0; Ks < 4; ++Ks) {
        u32x4 f0 = {L[0][Ks].x, L[0][Ks].y, L[1][Ks].x, L[1][Ks].y};
        u32x4 f1 = {L2[0][Ks].x, L2[0][Ks].y, L2[1][Ks].x, L2[1][Ks].y};
        afA[0][Ks] = __builtin_bit_cast(bfx8, f0);
        afA[1][Ks] = __builtin_bit_cast(bfx8, f1);
      }
      __builtin_amdgcn_sched_barrier(0);
#pragma unroll
      for (int Ks = 0; Ks < 4; ++Ks)
#pragma unroll
        for (int Mt = 0; Mt < 2; ++Mt)
#pragma unroll
          for (int Nt = 0; Nt < 6; ++Nt)
            acc[Mt][Nt] = __builtin_amdgcn_mfma_f32_16x16x32_bf16(afA[Mt][Ks], wf[Nt][Ks],
                                                                  acc[Mt][Nt], 0, 0, 0);
      // ---- phase B: drain rest, validate chunks 4-7 ----
      {
        asm volatile("s_waitcnt vmcnt(0)");
        int guard = 0;
        while (1) {
          u32 bad = 0;
#pragma unroll
          for (int Ks = 4; Ks < 8; ++Ks) {
            asm volatile("" : "+v"(L[0][Ks]), "+v"(L2[0][Ks]), "+v"(L[1][Ks]), "+v"(L2[1][Ks]));
            bad |= (L[0][Ks].z ^ etag) | (L2[0][Ks].z ^ etag) |
                   (L[1][Ks].z ^ etag) | (L2[1][Ks].z ^ etag);
          }
          if (__all((int)(bad == 0))) break;
          if (++guard > (1 << 18)) break;          // fail visibly, never hang
          __builtin_amdgcn_s_sleep(1);
          GISS(4) GISS(5) GISS(6) GISS(7)
          asm volatile("s_waitcnt vmcnt(0)");
        }
      }
      bfx8 afB[2][4];
#pragma unroll
      for (int Ks = 4; Ks < 8; ++Ks) {
        u32x4 f0 = {L[0][Ks].x, L[0][Ks].y, L[1][Ks].x, L[1][Ks].y};
        u32x4 f1 = {L2[0][Ks].x, L2[0][Ks].y, L2[1][Ks].x, L2[1][Ks].y};
        afB[0][Ks - 4] = __builtin_bit_cast(bfx8, f0);
        afB[1][Ks - 4] = __builtin_bit_cast(bfx8, f1);
      }
      // prefetch next step's x (shadowed by the B MFMA + dump/reduce phase)
      if (e < 127) {
        int tn = dir ? (126 - e) : (e + 1);
        const u16* xr = xpd + (size_t)(tn * 32 + eb) * NG + u0 + uu;
#pragma unroll
        for (int g = 0; g < 3; ++g) xn[g] = *(const u16x4*)(xr + g * U_);
      }
      __builtin_amdgcn_sched_barrier(0);
#pragma unroll
      for (int Ks = 0; Ks < 4; ++Ks)
#pragma unroll
        for (int Mt = 0; Mt < 2; ++Mt)
#pragma unroll
          for (int Nt = 0; Nt < 6; ++Nt)
            acc[Mt][Nt] = __builtin_amdgcn_mfma_f32_16x16x32_bf16(afB[Mt][Ks], wf[Nt][Ks + 4],
                                                                  acc[Mt][Nt], 0, 0, 0);
    } else {
      // e==0: rec contribution is zero; prefetch x for step 1
      int tn = dir ? 126 : 1;
      const u16* xr = xpd + (size_t)(tn * 32 + eb) * NG + u0 + uu;
#pragma unroll
      for (int g = 0; g < 3; ++g) xn[g] = *(const u16x4*)(xr + g * U_);
    }
    // dump partials: C/D layout col=lane&15, row=(lane>>4)*4+r
#pragma unroll
    for (int Mt = 0; Mt < 2; ++Mt)
#pragma unroll
      for (int Nt = 0; Nt < 6; ++Nt)
#pragma unroll
        for (int r = 0; r < 4; ++r)
          pl[wave][Mt * 16 + l4 * 4 + r][Nt * 16 + l15] = acc[Mt][Nt][r];
    __syncthreads();
    // reduce K-quarters + gates; publish FIRST, then deferred y (pre-update h)
    float hold[4];
#pragma unroll
    for (int j = 0; j < 4; ++j) hold[j] = hreg[j];
#pragma unroll
    for (int j = 0; j < 4; ++j) {
      int c = uu + j;
      float rz = pl[0][eb][c]      + pl[1][eb][c]      + pl[2][eb][c]      + pl[3][eb][c];
      float rr = pl[0][eb][32 + c] + pl[1][eb][32 + c] + pl[2][eb][32 + c] + pl[3][eb][32 + c];
      float rh = pl[0][eb][64 + c] + pl[1][eb][64 + c] + pl[2][eb][64 + c] + pl[3][eb][64 + c];
      float z  = sigm(bf2f(xc[0][j]) + rz + b1[0][j]);
      float r  = sigm(bf2f(xc[1][j]) + rr + b1[1][j]);
      float hh = ftanh(bf2f(xc[2][j]) + r * (rh + b1[2][j]));
      hreg[j] = z * hreg[j] + (1.f - z) * hh;
    }
    {
      u32 p01 = (u32)f2bf(hreg[0]) | ((u32)f2bf(hreg[1]) << 16);
      u32 p23 = (u32)f2bf(hreg[2]) | ((u32)f2bf(hreg[3]) << 16);
      u32x4 sv; sv.x = p01; sv.y = p23; sv.z = (u32)(e + 1); sv.w = (u32)(e + 1);
      char* sa = hxd + rs * ROTB + soff;
      asm volatile("global_store_dwordx4 %0, %1, off sc0 sc1" :: "v"(sa), "v"(sv));
    }
    // deferred y for epoch e-1. Safe: the gates' union over all 32 slices
    // proves every WG consumed XP row t(e-1) before publishing tag e.
    if (e > 0) {
      const int tp = dir ? (128 - e) : (e - 1);
      float* yrow = (float*)(xpd + (size_t)(tp * 32 + eb) * NG);
      *(float4*)(yrow + u0 + uu) = make_float4(hold[0], hold[1], hold[2], hold[3]);
    }
    xc[0] = xn[0]; xc[1] = xn[1]; xc[2] = xn[2];
    rl = rs; rs = (rs == 2) ? 0 : rs + 1;
    __syncthreads();          // protect pl against next epoch's dump
  }
  // final: wait for all 32 slices' tag-128 (rot 2), then last y row + states
  {
    const char* pa = hxd + 2 * ROTB + ((lane & 31) * 8 + 7) * 512 + 31 * 16;
    int g = 0;
    while (1) {
      u32 tv = 128u;
      if (lane < 32) {
        u32x4 tvv;
        asm volatile("global_load_dwordx4 %0, %1, off sc0 sc1\n\ts_waitcnt vmcnt(0)"
                     : "=v"(tvv) : "v"(pa));
        tv = tvv.z;
      }
      if (__all((int)(tv == 128u))) break;
      if (++g > (1 << 22)) break;
      __builtin_amdgcn_s_sleep(1);
    }
    const int tl = dir ? 0 : 127;
    float* yrow = (float*)(xpd + (size_t)(tl * 32 + eb) * NG);
    *(float4*)(yrow + u0 + uu) = make_float4(hreg[0], hreg[1], hreg[2], hreg[3]);
    float* os = out + YN + (size_t)dir * (B_ * U_) + (size_t)eb * U_ + u0 + uu;
    *(float4*)os = make_float4(hreg[0], hreg[1], hreg[2], hreg[3]);
  }
}

// ---------------- M: y merge  out = yf + yb ----------------
__global__ __launch_bounds__(256) void k_merge(const u16* __restrict__ XP,
                                               float* __restrict__ out) {
  int idx = blockIdx.x * 256 + threadIdx.x;
  int u4 = (idx & 255) * 4;
  int m = idx >> 8;                            // t*32+b
  int t = m >> 5, b = m & 31;
  const float* yf = (const float*)(XP + (size_t)m * NG);
  const float* yb = (const float*)(XP + (size_t)(M_ + m) * NG);
  float4 a = *(const float4*)(yf + u4);
  float4 c = *(const float4*)(yb + u4);
  float4 o; o.x = a.x + c.x; o.y = a.y + c.y; o.z = a.z + c.z; o.w = a.w + c.w;
  *(float4*)(out + ((size_t)b * T_ + t) * U_ + u4) = o;
}

extern "C" void kernel_launch(void* const* d_in, const int* in_sizes, int n_in,
                              void* d_out, int out_size, void* d_ws, size_t ws_size,
                              hipStream_t stream) {
  const int*   tokens = (const int*)d_in[0];
  const float* emb    = (const float*)d_in[1];
  const float* kf     = (const float*)d_in[2];
  const float* rkf    = (const float*)d_in[3];
  const float* bf_    = (const float*)d_in[4];
  const float* kb     = (const float*)d_in[5];
  const float* rkb    = (const float*)d_in[6];
  const float* bb_    = (const float*)d_in[7];
  float* out = (float*)d_out;
  char* ws = (char*)d_ws;

  u16*  X  = (u16*)ws;                        // 4 MB
  u16*  WT = (u16*)(ws + 0x400000);           // 6 MB
  char* Hx = ws + 0x400000;                   // 768 KB (aliases WT; WT dead post-xproj)
  u16*  RW = (u16*)(ws + 0xA00000);           // 12 MB
  u16*  XP = (u16*)(ws + 0x1600000);          // 48 MB (y stashed in row heads)

  k_embed<<<1024, 256, 0, stream>>>(tokens, emb, X);
  k_transpose_all<<<dim3(48, 96, 2), dim3(32, 8), 0, stream>>>(kf, kb, rkf, rkb, WT, RW);
  k_xproj<<<dim3(24, 32, 2), 256, 0, stream>>>(X, WT, bf_, bb_, XP);
  hipMemsetAsync(Hx, 0, 2 * HXD, stream);
  k_gru<<<64, 256, 0, stream>>>(RW, XP, bf_, bb_, Hx, out);
  k_merge<<<4096, 256, 0, stream>>>(XP, out);
}

// Round 13
// 592.002 us; speedup vs baseline: 2.7525x; 1.0471x over previous
//
#include <hip/hip_runtime.h>

// Bidirectional GRU (Keras reset_after) B=32,T=128,E=512,U=1024.
// embed-cast -> fused weight transpose -> x_proj GEMM -> persistent recurrent
// kernel (R11-proven 64-WG structure; epoch-tagged self-validating h exchange
// over sc0sc1, two-phase gate) with ONE isolated delta: per-step barriers are
// LDS-only (s_waitcnt lgkmcnt(0); s_barrier) so publish/y stores and x
// prefetches are never drained at barriers -> y merge.

using u16 = unsigned short;
using u32 = unsigned int;
typedef __attribute__((ext_vector_type(8))) short bfx8;
typedef __attribute__((ext_vector_type(4))) float f32x4;
typedef __attribute__((ext_vector_type(4))) u32 u32x4;
typedef __attribute__((ext_vector_type(4))) u16 u16x4;

#define B_ 32
#define T_ 128
#define E_ 512
#define U_ 1024
#define NG 3072
#define M_ 4096
#define YN 4194304
// Hx geometry: per dir, 3 rotating buffers; each [256 grp][32 b][16B]
// unit = {bf16 h[4g..4g+3] for row b (8B), u32 epoch tag, u32 tag copy}
#define ROTB 131072
#define HXD  393216

__device__ __forceinline__ float bf2f(u16 u) {
  union { u32 i; float f; } v; v.i = (u32)u << 16; return v.f;
}
__device__ __forceinline__ u16 f2bf(float f) {
  union { float f; u32 i; } v; v.f = f;
  u32 r = v.i + 0x7FFFu + ((v.i >> 16) & 1u);
  return (u16)(r >> 16);
}
__device__ __forceinline__ float sigm(float x) { return 1.0f / (1.0f + __expf(-x)); }
__device__ __forceinline__ float ftanh(float x) {
  float e = __expf(2.f * x);          // saturation-safe
  return 1.f - 2.f / (e + 1.f);
}

// barrier that drains ONLY LDS (lgkmcnt), leaving vmem loads/stores in flight.
// Safe here: barriers order only the pl dump/reduce; the h exchange is ordered
// by the tag protocol's data dependencies, not by barriers.
#define BAR_LDS() do { \
  asm volatile("s_waitcnt lgkmcnt(0)\n\ts_barrier" ::: "memory"); \
  __builtin_amdgcn_sched_barrier(0); \
} while (0)

__device__ __forceinline__ void load_lds16(const void* g, void* l) {
  __builtin_amdgcn_global_load_lds(
      (const __attribute__((address_space(1))) u32*)g,
      (__attribute__((address_space(3))) u32*)l, 16, 0, 0);
}

// ---------------- P1: embedding gather + cast ----------------
__global__ __launch_bounds__(256) void k_embed(const int* __restrict__ tok,
                                               const float* __restrict__ emb,
                                               u16* __restrict__ X) {
  int idx = blockIdx.x * 256 + threadIdx.x;
  int m = idx >> 6, k8 = (idx & 63) << 3;
  int b = m & 31, t = m >> 5;
  int tk = tok[b * T_ + t];
  const float* s = emb + (size_t)tk * E_ + k8;
  float4 v0 = *(const float4*)s, v1 = *(const float4*)(s + 4);
  bfx8 r;
  r[0]=(short)f2bf(v0.x); r[1]=(short)f2bf(v0.y); r[2]=(short)f2bf(v0.z); r[3]=(short)f2bf(v0.w);
  r[4]=(short)f2bf(v1.x); r[5]=(short)f2bf(v1.y); r[6]=(short)f2bf(v1.z); r[7]=(short)f2bf(v1.w);
  *(bfx8*)(X + (size_t)m * E_ + k8) = r;
}

// ---------------- P2: fused transpose/cast of all 4 weight matrices ----------------
__global__ void k_transpose_all(const float* __restrict__ kf, const float* __restrict__ kb,
                                const float* __restrict__ rkf, const float* __restrict__ rkb,
                                u16* __restrict__ WT, u16* __restrict__ RW) {
  __shared__ float tile[32][33];
  const int z = blockIdx.z;
  const float* in; u16* outp; int K, remap, bx;
  if (blockIdx.x < 16) { in = z ? kb : kf;   outp = WT + (size_t)z * 3072 * 512;  K = 512;  remap = 0; bx = blockIdx.x; }
  else                 { in = z ? rkb : rkf; outp = RW + (size_t)z * 3072 * 1024; K = 1024; remap = 1; bx = blockIdx.x - 16; }
  int k0 = bx * 32, n0 = blockIdx.y * 32;
  int tx = threadIdx.x, ty = threadIdx.y;
  for (int j = ty; j < 32; j += 8) tile[j][tx] = in[(size_t)(k0 + j) * NG + n0 + tx];
  __syncthreads();
  for (int j = ty; j < 32; j += 8) {
    int n = n0 + j;
    int row = remap ? ((((n & 1023) >> 5) * 96) + ((n >> 10) << 5) + (n & 31)) : n;
    outp[(size_t)row * K + k0 + tx] = f2bf(tile[tx][j]);
  }
}

// ---------------- G: x_proj GEMM ----------------
__global__ __launch_bounds__(256) void k_xproj(const u16* __restrict__ X,
                                               const u16* __restrict__ WT,
                                               const float* __restrict__ biasF,
                                               const float* __restrict__ biasB,
                                               u16* __restrict__ XP) {
  const int n0 = blockIdx.x * 128, m0 = blockIdx.y * 128, dir = blockIdx.z;
  const float* bias = dir ? biasB : biasF;
  const u16* Wd = WT + (size_t)dir * NG * E_;
  __shared__ __align__(16) u16 As[128 * 64];
  __shared__ __align__(16) u16 Bs[128 * 64];
  const int tid = threadIdx.x;
  const int wave = tid >> 6, lane = tid & 63;
  const int moff = (wave >> 1) * 64, noff = (wave & 1) * 64;
  const int l15 = lane & 15, l4 = lane >> 4;
  f32x4 acc[4][4] = {};
  for (int kt = 0; kt < 8; ++kt) {
    int k0 = kt * 64;
#pragma unroll
    for (int j = 0; j < 4; ++j) {
      int o = j * 4096 + tid * 16;
      int row = o >> 7;
      int kk = (((o & 127) ^ ((row & 7) << 4)) >> 1);
      load_lds16(X  + (size_t)(m0 + row) * E_ + k0 + kk, (char*)As + o);
      load_lds16(Wd + (size_t)(n0 + row) * E_ + k0 + kk, (char*)Bs + o);
    }
    __syncthreads();
#pragma unroll
    for (int Ks = 0; Ks < 2; ++Ks) {
      bfx8 a[4], b[4];
#pragma unroll
      for (int Mt = 0; Mt < 4; ++Mt) {
        int ra = moff + Mt * 16 + l15;
        int ba = (ra << 7) + ((Ks * 32 + l4 * 8) << 1);
        ba ^= (ra & 7) << 4;
        a[Mt] = *(const bfx8*)((const char*)As + ba);
      }
#pragma unroll
      for (int Nt = 0; Nt < 4; ++Nt) {
        int rb = noff + Nt * 16 + l15;
        int bb2 = (rb << 7) + ((Ks * 32 + l4 * 8) << 1);
        bb2 ^= (rb & 7) << 4;
        b[Nt] = *(const bfx8*)((const char*)Bs + bb2);
      }
#pragma unroll
      for (int Mt = 0; Mt < 4; ++Mt)
#pragma unroll
        for (int Nt = 0; Nt < 4; ++Nt)
          acc[Mt][Nt] = __builtin_amdgcn_mfma_f32_16x16x32_bf16(a[Mt], b[Nt], acc[Mt][Nt], 0, 0, 0);
    }
    __syncthreads();
  }
  float bv[4];
#pragma unroll
  for (int Nt = 0; Nt < 4; ++Nt) bv[Nt] = bias[n0 + noff + Nt * 16 + l15];
#pragma unroll
  for (int Mt = 0; Mt < 4; ++Mt)
#pragma unroll
    for (int Nt = 0; Nt < 4; ++Nt)
#pragma unroll
      for (int r = 0; r < 4; ++r) {
        int m = m0 + moff + Mt * 16 + l4 * 4 + r;
        int n = n0 + noff + Nt * 16 + l15;
        XP[((size_t)dir * M_ + m) * NG + n] = f2bf(acc[Mt][Nt][r] + bv[Nt]);
      }
}

// ---------------- R: persistent recurrent kernel ----------------
// 64 WGs = 2 dirs x 32 slices. Epoch-tagged 16B units; TWO-PHASE gate (R11):
// loads issued and consumed INSIDE the gate block (short window — R12 lesson:
// asm load dests must not live across barriers/back-edges). LDS-only barriers.
#define GISS(Ks) { \
  const char* a_ = rbase + offb + (Ks) * 4096; \
  asm volatile("global_load_dwordx4 %0, %1, off sc0 sc1"             : "=v"(L[0][Ks])  : "v"(a_)); \
  asm volatile("global_load_dwordx4 %0, %1, off offset:256 sc0 sc1" : "=v"(L2[0][Ks]) : "v"(a_)); \
  asm volatile("global_load_dwordx4 %0, %1, off offset:512 sc0 sc1" : "=v"(L[1][Ks])  : "v"(a_)); \
  asm volatile("global_load_dwordx4 %0, %1, off offset:768 sc0 sc1" : "=v"(L2[1][Ks]) : "v"(a_)); }

__global__ __launch_bounds__(256, 1) void k_gru(
    const u16* __restrict__ RW,
    u16* __restrict__ XP,
    const float* __restrict__ bf_, const float* __restrict__ bb_,
    char* __restrict__ Hx,
    float* __restrict__ out) {
  const int tid = threadIdx.x;
  const int wave = tid >> 6, lane = tid & 63;
  const int wg = blockIdx.x;
  const int dir = wg & 1, slice = wg >> 1;
  const int u0 = slice * 32;
  const float* b1p = (dir ? bb_ : bf_) + NG;
  const u16* wbase = RW + (size_t)dir * NG * U_ + (size_t)slice * 96 * U_;
  u16* xpd = XP + (size_t)dir * M_ * NG;
  char* hxd = Hx + (size_t)dir * HXD;
  __shared__ float pl[4][32][97];

  const int l15 = lane & 15, l4 = lane >> 4;

  // preload this wave's 48 weight frags — resident all 128 steps
  bfx8 wf[6][8];
#pragma unroll
  for (int Nt = 0; Nt < 6; ++Nt)
#pragma unroll
    for (int Ks = 0; Ks < 8; ++Ks) {
      int c = Nt * 16 + l15;
      int k = wave * 256 + Ks * 32 + l4 * 8;
      wf[Nt][Ks] = *(const bfx8*)(wbase + (size_t)c * U_ + k);
    }

  // epilogue mapping: thread owns (b=eb, cols u0+uu..u0+uu+3)
  const int eb = tid & 31;
  const int ug = tid >> 5;
  const int uu = ug * 4;
  float b1[3][4];
#pragma unroll
  for (int g = 0; g < 3; ++g)
#pragma unroll
    for (int j = 0; j < 4; ++j) b1[g][j] = b1p[g * U_ + u0 + uu + j];
  float hreg[4] = {0.f, 0.f, 0.f, 0.f};

  const int offb = wave * 32768 + l4 * 1024 + l15 * 16;          // consumer bulk base
  const int soff = (slice * 8 + ug) * 512 + eb * 16;             // producer unit

  // xc holds CURRENT step's x; loaded up-front for step 0
  u16x4 xc[3];
  {
    int t0 = dir ? 127 : 0;
    const u16* xr = xpd + (size_t)(t0 * 32 + eb) * NG + u0 + uu;
#pragma unroll
    for (int g = 0; g < 3; ++g) xc[g] = *(const u16x4*)(xr + g * U_);
  }

  int rl = 0, rs = 1;                              // rl = e%3, rs = (e+1)%3
  for (int e = 0; e < 128; ++e) {
    f32x4 acc[2][6] = {};
    u16x4 xn[3] = {xc[0], xc[1], xc[2]};           // next-step x (default keep)
    if (e > 0) {
      const u32 etag = (u32)e;
      char* rbase = hxd + rl * ROTB;
      u32x4 L[2][8], L2[2][8];
      // issue ALL 32 unit loads: group A (Ks 0-3) oldest, group B (Ks 4-7)
      GISS(0) GISS(1) GISS(2) GISS(3)
      GISS(4) GISS(5) GISS(6) GISS(7)
      // ---- phase A: vmcnt(16) -> in-order retirement means A retired ----
      {
        asm volatile("s_waitcnt vmcnt(16)");
        int guard = 0;
        while (1) {
          u32 bad = 0;
#pragma unroll
          for (int Ks = 0; Ks < 4; ++Ks) {
            asm volatile("" : "+v"(L[0][Ks]), "+v"(L2[0][Ks]), "+v"(L[1][Ks]), "+v"(L2[1][Ks]));
            bad |= (L[0][Ks].z ^ etag) | (L2[0][Ks].z ^ etag) |
                   (L[1][Ks].z ^ etag) | (L2[1][Ks].z ^ etag);
          }
          if (__all((int)(bad == 0))) break;
          if (++guard > (1 << 18)) break;          // fail visibly, never hang
          __builtin_amdgcn_s_sleep(1);
          GISS(0) GISS(1) GISS(2) GISS(3)
          asm volatile("s_waitcnt vmcnt(0)");
        }
      }
      bfx8 afA[2][4];
#pragma unroll
      for (int Ks = 0; Ks < 4; ++Ks) {
        u32x4 f0 = {L[0][Ks].x, L[0][Ks].y, L[1][Ks].x, L[1][Ks].y};
        u32x4 f1 = {L2[0][Ks].x, L2[0][Ks].y, L2[1][Ks].x, L2[1][Ks].y};
        afA[0][Ks] = __builtin_bit_cast(bfx8, f0);
        afA[1][Ks] = __builtin_bit_cast(bfx8, f1);
      }
      __builtin_amdgcn_sched_barrier(0);
#pragma unroll
      for (int Ks = 0; Ks < 4; ++Ks)
#pragma unroll
        for (int Mt = 0; Mt < 2; ++Mt)
#pragma unroll
          for (int Nt = 0; Nt < 6; ++Nt)
            acc[Mt][Nt] = __builtin_amdgcn_mfma_f32_16x16x32_bf16(afA[Mt][Ks], wf[Nt][Ks],
                                                                  acc[Mt][Nt], 0, 0, 0);
      // ---- phase B: drain rest, validate chunks 4-7 ----
      {
        asm volatile("s_waitcnt vmcnt(0)");
        int guard = 0;
        while (1) {
          u32 bad = 0;
#pragma unroll
          for (int Ks = 4; Ks < 8; ++Ks) {
            asm volatile("" : "+v"(L[0][Ks]), "+v"(L2[0][Ks]), "+v"(L[1][Ks]), "+v"(L2[1][Ks]));
            bad |= (L[0][Ks].z ^ etag) | (L2[0][Ks].z ^ etag) |
                   (L[1][Ks].z ^ etag) | (L2[1][Ks].z ^ etag);
          }
          if (__all((int)(bad == 0))) break;
          if (++guard > (1 << 18)) break;          // fail visibly, never hang
          __builtin_amdgcn_s_sleep(1);
          GISS(4) GISS(5) GISS(6) GISS(7)
          asm volatile("s_waitcnt vmcnt(0)");
        }
      }
      bfx8 afB[2][4];
#pragma unroll
      for (int Ks = 4; Ks < 8; ++Ks) {
        u32x4 f0 = {L[0][Ks].x, L[0][Ks].y, L[1][Ks].x, L[1][Ks].y};
        u32x4 f1 = {L2[0][Ks].x, L2[0][Ks].y, L2[1][Ks].x, L2[1][Ks].y};
        afB[0][Ks - 4] = __builtin_bit_cast(bfx8, f0);
        afB[1][Ks - 4] = __builtin_bit_cast(bfx8, f1);
      }
      // prefetch next step's x (shadowed by the B MFMA + dump/reduce phase)
      if (e < 127) {
        int tn = dir ? (126 - e) : (e + 1);
        const u16* xr = xpd + (size_t)(tn * 32 + eb) * NG + u0 + uu;
#pragma unroll
        for (int g = 0; g < 3; ++g) xn[g] = *(const u16x4*)(xr + g * U_);
      }
      __builtin_amdgcn_sched_barrier(0);
#pragma unroll
      for (int Ks = 0; Ks < 4; ++Ks)
#pragma unroll
        for (int Mt = 0; Mt < 2; ++Mt)
#pragma unroll
          for (int Nt = 0; Nt < 6; ++Nt)
            acc[Mt][Nt] = __builtin_amdgcn_mfma_f32_16x16x32_bf16(afB[Mt][Ks], wf[Nt][Ks + 4],
                                                                  acc[Mt][Nt], 0, 0, 0);
    } else {
      // e==0: rec contribution is zero; prefetch x for step 1
      int tn = dir ? 126 : 1;
      const u16* xr = xpd + (size_t)(tn * 32 + eb) * NG + u0 + uu;
#pragma unroll
      for (int g = 0; g < 3; ++g) xn[g] = *(const u16x4*)(xr + g * U_);
    }
    // dump partials: C/D layout col=lane&15, row=(lane>>4)*4+r
#pragma unroll
    for (int Mt = 0; Mt < 2; ++Mt)
#pragma unroll
      for (int Nt = 0; Nt < 6; ++Nt)
#pragma unroll
        for (int r = 0; r < 4; ++r)
          pl[wave][Mt * 16 + l4 * 4 + r][Nt * 16 + l15] = acc[Mt][Nt][r];
    BAR_LDS();                                     // LDS-only: vmem stays in flight
    // reduce K-quarters + gates; publish FIRST, then deferred y (pre-update h)
    float hold[4];
#pragma unroll
    for (int j = 0; j < 4; ++j) hold[j] = hreg[j];
#pragma unroll
    for (int j = 0; j < 4; ++j) {
      int c = uu + j;
      float rz = pl[0][eb][c]      + pl[1][eb][c]      + pl[2][eb][c]      + pl[3][eb][c];
      float rr = pl[0][eb][32 + c] + pl[1][eb][32 + c] + pl[2][eb][32 + c] + pl[3][eb][32 + c];
      float rh = pl[0][eb][64 + c] + pl[1][eb][64 + c] + pl[2][eb][64 + c] + pl[3][eb][64 + c];
      float z  = sigm(bf2f(xc[0][j]) + rz + b1[0][j]);
      float r  = sigm(bf2f(xc[1][j]) + rr + b1[1][j]);
      float hh = ftanh(bf2f(xc[2][j]) + r * (rh + b1[2][j]));
      hreg[j] = z * hreg[j] + (1.f - z) * hh;
    }
    {
      u32 p01 = (u32)f2bf(hreg[0]) | ((u32)f2bf(hreg[1]) << 16);
      u32 p23 = (u32)f2bf(hreg[2]) | ((u32)f2bf(hreg[3]) << 16);
      u32x4 sv; sv.x = p01; sv.y = p23; sv.z = (u32)(e + 1); sv.w = (u32)(e + 1);
      char* sa = hxd + rs * ROTB + soff;
      asm volatile("global_store_dwordx4 %0, %1, off sc0 sc1" :: "v"(sa), "v"(sv));
    }
    // deferred y for epoch e-1. Safe: tag-e visibility data-depends on each
    // producer's epoch-(e-1) x loads (through its hreg chain) => every WG
    // consumed XP row t(e-1) before its tag e became visible.
    if (e > 0) {
      const int tp = dir ? (128 - e) : (e - 1);
      float* yrow = (float*)(xpd + (size_t)(tp * 32 + eb) * NG);
      *(float4*)(yrow + u0 + uu) = make_float4(hold[0], hold[1], hold[2], hold[3]);
    }
    xc[0] = xn[0]; xc[1] = xn[1]; xc[2] = xn[2];
    rl = rs; rs = (rs == 2) ? 0 : rs + 1;
    BAR_LDS();                                     // protect pl; vmem in flight
  }
  // final: wait for all 32 slices' tag-128 (rot 2), then last y row + states
  {
    const char* pa = hxd + 2 * ROTB + ((lane & 31) * 8 + 7) * 512 + 31 * 16;
    int g = 0;
    while (1) {
      u32 tv = 128u;
      if (lane < 32) {
        u32x4 tvv;
        asm volatile("global_load_dwordx4 %0, %1, off sc0 sc1\n\ts_waitcnt vmcnt(0)"
                     : "=v"(tvv) : "v"(pa));
        tv = tvv.z;
      }
      if (__all((int)(tv == 128u))) break;
      if (++g > (1 << 22)) break;
      __builtin_amdgcn_s_sleep(1);
    }
    const int tl = dir ? 0 : 127;
    float* yrow = (float*)(xpd + (size_t)(tl * 32 + eb) * NG);
    *(float4*)(yrow + u0 + uu) = make_float4(hreg[0], hreg[1], hreg[2], hreg[3]);
    float* os = out + YN + (size_t)dir * (B_ * U_) + (size_t)eb * U_ + u0 + uu;
    *(float4*)os = make_float4(hreg[0], hreg[1], hreg[2], hreg[3]);
  }
}

// ---------------- M: y merge  out = yf + yb ----------------
__global__ __launch_bounds__(256) void k_merge(const u16* __restrict__ XP,
                                               float* __restrict__ out) {
  int idx = blockIdx.x * 256 + threadIdx.x;
  int u4 = (idx & 255) * 4;
  int m = idx >> 8;                            // t*32+b
  int t = m >> 5, b = m & 31;
  const float* yf = (const float*)(XP + (size_t)m * NG);
  const float* yb = (const float*)(XP + (size_t)(M_ + m) * NG);
  float4 a = *(const float4*)(yf + u4);
  float4 c = *(const float4*)(yb + u4);
  float4 o; o.x = a.x + c.x; o.y = a.y + c.y; o.z = a.z + c.z; o.w = a.w + c.w;
  *(float4*)(out + ((size_t)b * T_ + t) * U_ + u4) = o;
}

extern "C" void kernel_launch(void* const* d_in, const int* in_sizes, int n_in,
                              void* d_out, int out_size, void* d_ws, size_t ws_size,
                              hipStream_t stream) {
  const int*   tokens = (const int*)d_in[0];
  const float* emb    = (const float*)d_in[1];
  const float* kf     = (const float*)d_in[2];
  const float* rkf    = (const float*)d_in[3];
  const float* bf_    = (const float*)d_in[4];
  const float* kb     = (const float*)d_in[5];
  const float* rkb    = (const float*)d_in[6];
  const float* bb_    = (const float*)d_in[7];
  float* out = (float*)d_out;
  char* ws = (char*)d_ws;

  u16*  X  = (u16*)ws;                        // 4 MB
  u16*  WT = (u16*)(ws + 0x400000);           // 6 MB
  char* Hx = ws + 0x400000;                   // 768 KB (aliases WT; WT dead post-xproj)
  u16*  RW = (u16*)(ws + 0xA00000);           // 12 MB
  u16*  XP = (u16*)(ws + 0x1600000);          // 48 MB (y stashed in row heads)

  k_embed<<<1024, 256, 0, stream>>>(tokens, emb, X);
  k_transpose_all<<<dim3(48, 96, 2), dim3(32, 8), 0, stream>>>(kf, kb, rkf, rkb, WT, RW);
  k_xproj<<<dim3(24, 32, 2), 256, 0, stream>>>(X, WT, bf_, bb_, XP);
  hipMemsetAsync(Hx, 0, 2 * HXD, stream);
  k_gru<<<64, 256, 0, stream>>>(RW, XP, bf_, bb_, Hx, out);
  k_merge<<<4096, 256, 0, stream>>>(XP, out);
}